// Round 1
// baseline (847.080 us; speedup 1.0000x reference)
//
#include <hip/hip_runtime.h>
#include <stdint.h>

// ---------------------------------------------------------------------------
// GCN 2-layer: out = GCNConv(relu(GCNConv(x, W1,b1)), W2,b2)
// deg[c] = sum ew over edges into c (col is destination), dis = rsqrt(deg+1)
// agg[c] = dis[c] * sum_e( dis[row_e]*ew_e * xw[row_e] ) + dis[c]^2 * xw[c]
// ---------------------------------------------------------------------------

// Detect int64 vs int32 edge_index layout: int64 little-endian values < 2^31
// have zero hi-words at every odd int32 slot.
__global__ void detect_kernel(const int* __restrict__ ei, int* flag) {
    if (threadIdx.x == 0 && blockIdx.x == 0) {
        int z = 0;
        for (int i = 0; i < 16; ++i) z |= ei[2 * i + 1];
        *flag = (z == 0) ? 1 : 0;
    }
}

__global__ void count_kernel(const void* __restrict__ ei, const float* __restrict__ ew,
                             int* __restrict__ cnt, float* __restrict__ deg,
                             int E, const int* __restrict__ flag) {
    const int is64 = *flag;
    const int* e32 = (const int*)ei;
    const long long* e64 = (const long long*)ei;
    for (int e = blockIdx.x * blockDim.x + threadIdx.x; e < E;
         e += gridDim.x * blockDim.x) {
        int c = is64 ? (int)e64[(size_t)E + e] : e32[(size_t)E + e];
        atomicAdd(&cnt[c], 1);
        atomicAdd(&deg[c], ew[e]);
    }
}

// Single-block exclusive scan over cnt[0..n) -> ptr[0..n]
__global__ __launch_bounds__(1024) void scan_kernel(const int* __restrict__ cnt,
                                                    int* __restrict__ ptr, int n) {
    __shared__ int sm[1024];
    const int t = threadIdx.x;
    const int chunk = (n + 1023) / 1024;
    const int start = t * chunk;
    const int end = min(start + chunk, n);
    int s = 0;
    for (int i = start; i < end; ++i) s += cnt[i];
    sm[t] = s;
    __syncthreads();
    for (int off = 1; off < 1024; off <<= 1) {
        int v = (t >= off) ? sm[t - off] : 0;
        __syncthreads();
        sm[t] += v;
        __syncthreads();
    }
    int run = (t == 0) ? 0 : sm[t - 1];
    for (int i = start; i < end; ++i) { ptr[i] = run; run += cnt[i]; }
    if (start < n && end == n) ptr[n] = run;
}

__global__ void dis_kernel(const float* __restrict__ deg, float* __restrict__ dis, int n) {
    int i = blockIdx.x * blockDim.x + threadIdx.x;
    if (i < n) dis[i] = rsqrtf(deg[i] + 1.0f);
}

__global__ void scatter_kernel(const void* __restrict__ ei, const float* __restrict__ ew,
                               const float* __restrict__ dis, const int* __restrict__ ptr,
                               int* __restrict__ cur, int* __restrict__ rows_s,
                               float* __restrict__ ws_s, int E, const int* __restrict__ flag) {
    const int is64 = *flag;
    const int* e32 = (const int*)ei;
    const long long* e64 = (const long long*)ei;
    for (int e = blockIdx.x * blockDim.x + threadIdx.x; e < E;
         e += gridDim.x * blockDim.x) {
        int r, c;
        if (is64) { r = (int)e64[e]; c = (int)e64[(size_t)E + e]; }
        else      { r = e32[e];      c = e32[(size_t)E + e]; }
        int pos = ptr[c] + atomicAdd(&cur[c], 1);
        rows_s[pos] = r;
        ws_s[pos] = dis[r] * ew[e];
    }
}

// Y[n,DOUT] = X[n,128] @ W[128,DOUT].  W transposed into LDS (pad 132 for
// conflict-free float4 reads), X tile (ROWS x 128) in LDS (uniform-address
// broadcast reads per wave).
template <int DOUT, int ROWS>
__global__ __launch_bounds__(256) void gemm_kernel(const float* __restrict__ X,
                                                   const float* __restrict__ W,
                                                   float* __restrict__ Y, int n) {
    constexpr int GROUPS = 256 / DOUT;     // 2 for DOUT=128, 4 for DOUT=64
    constexpr int R = ROWS / GROUPS;       // rows per thread
    __shared__ float Wt[DOUT * 132];
    __shared__ float Xl[ROWS * 128];
    const int t = threadIdx.x;
    const int row0 = blockIdx.x * ROWS;

    for (int i = t; i < 128 * DOUT; i += 256) {
        int k = i / DOUT, c = i % DOUT;
        Wt[c * 132 + k] = W[i];
    }
    for (int i = t * 4; i < ROWS * 128; i += 256 * 4) {
        int r = row0 + i / 128;
        float4 v = {0.f, 0.f, 0.f, 0.f};
        if (r < n) v = *(const float4*)(X + (size_t)row0 * 128 + i);
        *(float4*)(Xl + i) = v;
    }
    __syncthreads();

    const int col = t % DOUT;
    const int rg = t / DOUT;
    float acc[R];
#pragma unroll
    for (int i = 0; i < R; ++i) acc[i] = 0.f;

    for (int k = 0; k < 128; k += 4) {
        float4 w4 = *(const float4*)(Wt + col * 132 + k);
#pragma unroll
        for (int i = 0; i < R; ++i) {
            float4 x4 = *(const float4*)(Xl + (rg * R + i) * 128 + k);
            acc[i] += x4.x * w4.x + x4.y * w4.y + x4.z * w4.z + x4.w * w4.w;
        }
    }
#pragma unroll
    for (int i = 0; i < R; ++i) {
        int r = row0 + rg * R + i;
        if (r < n) Y[(size_t)r * DOUT + col] = acc[i];
    }
}

// One wave per node. D=128: lane holds 2 dims (float2); D=64: 1 dim.
template <int D>
__global__ __launch_bounds__(256) void prop_kernel(const float* __restrict__ xw,
                                                   const float* __restrict__ dis,
                                                   const int* __restrict__ ptr,
                                                   const int* __restrict__ rows_s,
                                                   const float* __restrict__ ws_s,
                                                   const float* __restrict__ bias,
                                                   float* __restrict__ out,
                                                   int n, int do_relu) {
    const int wid = threadIdx.x >> 6;
    const int lane = threadIdx.x & 63;
    const int v = blockIdx.x * 4 + wid;
    if (v >= n) return;

    const float dv = dis[v];
    const int beg = ptr[v];
    const int end = ptr[v + 1];

    float acc0 = 0.f, acc1 = 0.f;
    for (int base = beg; base < end; base += 64) {
        const int m = end - base;
        int r_l = 0;
        float w_l = 0.f;
        if (lane < m) {
            r_l = rows_s[base + lane];
            w_l = ws_s[base + lane];
        }
        const int lim = m < 64 ? m : 64;
        for (int j = 0; j < lim; ++j) {
            int r = __shfl(r_l, j);
            float w = __shfl(w_l, j);
            if (D == 128) {
                float2 xv = *(const float2*)(xw + (size_t)r * 128 + lane * 2);
                acc0 += w * xv.x;
                acc1 += w * xv.y;
            } else {
                float xv = xw[(size_t)r * 64 + lane];
                acc0 += w * xv;
            }
        }
    }

    if (D == 128) {
        float2 xv = *(const float2*)(xw + (size_t)v * 128 + lane * 2);
        float r0 = dv * acc0 + dv * dv * xv.x + bias[lane * 2];
        float r1 = dv * acc1 + dv * dv * xv.y + bias[lane * 2 + 1];
        if (do_relu) { r0 = fmaxf(r0, 0.f); r1 = fmaxf(r1, 0.f); }
        float2 o = {r0, r1};
        *(float2*)(out + (size_t)v * 128 + lane * 2) = o;
    } else {
        float xv = xw[(size_t)v * 64 + lane];
        float r0 = dv * acc0 + dv * dv * xv + bias[lane];
        if (do_relu) r0 = fmaxf(r0, 0.f);
        out[(size_t)v * 64 + lane] = r0;
    }
}

extern "C" void kernel_launch(void* const* d_in, const int* in_sizes, int n_in,
                              void* d_out, int out_size, void* d_ws, size_t ws_size,
                              hipStream_t stream) {
    const float* x  = (const float*)d_in[0];
    const void*  ei = d_in[1];
    const float* ew = (const float*)d_in[2];
    const float* W1 = (const float*)d_in[3];
    const float* b1 = (const float*)d_in[4];
    const float* W2 = (const float*)d_in[5];
    const float* b2 = (const float*)d_in[6];
    float* out = (float*)d_out;

    const int n = in_sizes[0] / 128;
    const int E = in_sizes[2];

    char* p = (char*)d_ws;
    size_t o = 0;
    auto alloc = [&](size_t bytes) -> void* {
        void* q = p + o;
        o += (bytes + 255) & ~(size_t)255;
        return q;
    };
    int*   flag   = (int*)alloc(4);
    int*   cnt    = (int*)alloc((size_t)n * 4);
    float* deg    = (float*)alloc((size_t)n * 4);
    int*   ptr    = (int*)alloc(((size_t)n + 1) * 4);
    float* dis    = (float*)alloc((size_t)n * 4);
    int*   rows_s = (int*)alloc((size_t)E * 4);
    float* ws_s   = (float*)alloc((size_t)E * 4);
    float* bufA   = (float*)alloc((size_t)n * 128 * 4);  // xw1, later xw2
    float* bufB   = (float*)alloc((size_t)n * 128 * 4);  // h

    hipMemsetAsync(cnt, 0, (size_t)n * 4, stream);
    hipMemsetAsync(deg, 0, (size_t)n * 4, stream);
    detect_kernel<<<1, 64, 0, stream>>>((const int*)ei, flag);
    count_kernel<<<2048, 256, 0, stream>>>(ei, ew, cnt, deg, E, flag);
    scan_kernel<<<1, 1024, 0, stream>>>(cnt, ptr, n);
    dis_kernel<<<(n + 255) / 256, 256, 0, stream>>>(deg, dis, n);
    hipMemsetAsync(cnt, 0, (size_t)n * 4, stream);
    scatter_kernel<<<2048, 256, 0, stream>>>(ei, ew, dis, ptr, cnt, rows_s, ws_s, E, flag);

    gemm_kernel<128, 64><<<(n + 63) / 64, 256, 0, stream>>>(x, W1, bufA, n);
    prop_kernel<128><<<(n + 3) / 4, 256, 0, stream>>>(bufA, dis, ptr, rows_s, ws_s, b1, bufB, n, 1);
    gemm_kernel<64, 64><<<(n + 63) / 64, 256, 0, stream>>>(bufB, W2, bufA, n);
    prop_kernel<64><<<(n + 3) / 4, 256, 0, stream>>>(bufA, dis, ptr, rows_s, ws_s, b2, out, n, 0);
}

// Round 2
// 827.550 us; speedup vs baseline: 1.0236x; 1.0236x over previous
//
#include <hip/hip_runtime.h>
#include <stdint.h>

// ---------------------------------------------------------------------------
// GCN 2-layer: out = GCNConv(relu(GCNConv(x, W1,b1)), W2,b2)
// deg[c] = sum ew over edges into c (col is destination), dis = rsqrt(deg+1)
// agg[c] = dis[c] * sum_e( dis[row_e]*ew_e * xw[row_e] ) + dis[c]^2 * xw[c]
// ---------------------------------------------------------------------------

// Detect int64 vs int32 edge_index layout: int64 little-endian values < 2^31
// have zero hi-words at every odd int32 slot.
__global__ void detect_kernel(const int* __restrict__ ei, int* flag) {
    if (threadIdx.x == 0 && blockIdx.x == 0) {
        int z = 0;
        for (int i = 0; i < 16; ++i) z |= ei[2 * i + 1];
        *flag = (z == 0) ? 1 : 0;
    }
}

__global__ void count_kernel(const void* __restrict__ ei, const float* __restrict__ ew,
                             int* __restrict__ cnt, float* __restrict__ deg,
                             int E, const int* __restrict__ flag) {
    const int is64 = *flag;
    const int* e32 = (const int*)ei;
    const long long* e64 = (const long long*)ei;
    for (int e = blockIdx.x * blockDim.x + threadIdx.x; e < E;
         e += gridDim.x * blockDim.x) {
        int c = is64 ? (int)e64[(size_t)E + e] : e32[(size_t)E + e];
        atomicAdd(&cnt[c], 1);
        atomicAdd(&deg[c], ew[e]);
    }
}

// Single-block exclusive scan over cnt[0..n) -> ptr[0..n]
__global__ __launch_bounds__(1024) void scan_kernel(const int* __restrict__ cnt,
                                                    int* __restrict__ ptr, int n) {
    __shared__ int sm[1024];
    const int t = threadIdx.x;
    const int chunk = (n + 1023) / 1024;
    const int start = t * chunk;
    const int end = min(start + chunk, n);
    int s = 0;
    for (int i = start; i < end; ++i) s += cnt[i];
    sm[t] = s;
    __syncthreads();
    for (int off = 1; off < 1024; off <<= 1) {
        int v = (t >= off) ? sm[t - off] : 0;
        __syncthreads();
        sm[t] += v;
        __syncthreads();
    }
    int run = (t == 0) ? 0 : sm[t - 1];
    for (int i = start; i < end; ++i) { ptr[i] = run; run += cnt[i]; }
    if (start < n && end == n) ptr[n] = run;
}

__global__ void dis_kernel(const float* __restrict__ deg, float* __restrict__ dis, int n) {
    int i = blockIdx.x * blockDim.x + threadIdx.x;
    if (i < n) dis[i] = rsqrtf(deg[i] + 1.0f);
}

__global__ void scatter_kernel(const void* __restrict__ ei, const float* __restrict__ ew,
                               const float* __restrict__ dis, const int* __restrict__ ptr,
                               int* __restrict__ cur, int* __restrict__ rows_s,
                               float* __restrict__ ws_s, int E, const int* __restrict__ flag) {
    const int is64 = *flag;
    const int* e32 = (const int*)ei;
    const long long* e64 = (const long long*)ei;
    for (int e = blockIdx.x * blockDim.x + threadIdx.x; e < E;
         e += gridDim.x * blockDim.x) {
        int r, c;
        if (is64) { r = (int)e64[e]; c = (int)e64[(size_t)E + e]; }
        else      { r = e32[e];      c = e32[(size_t)E + e]; }
        int pos = ptr[c] + atomicAdd(&cur[c], 1);
        rows_s[pos] = r;
        ws_s[pos] = dis[r] * ew[e];
    }
}

// ---------------------------------------------------------------------------
// Y[n,DOUT] = X[n,128] @ W[128,DOUT], fp32 vector-ALU GEMM.
// 256 threads, BM=128 rows, full K=128 staged once (no barriers in main loop).
// Xl[m][k] row-major + XOR bank-swizzle on k; Wt[n][k] = W^T, same swizzle.
// Thread (tm=t&15, tn=t>>4) computes rows tm*8..+8, cols tn*TN..+TN (TN=DOUT/16).
// Per 4-k step: 8+TN ds_read_b128 -> 8*TN*4 v_fmac (conflict-free by design:
// X read = 16 rows -> 8 bank-slots x 2-way (free); W read = 4 slots, bcast).
// ---------------------------------------------------------------------------
template <int DOUT>
__global__ __launch_bounds__(256) void gemm_kernel(const float* __restrict__ X,
                                                   const float* __restrict__ W,
                                                   float* __restrict__ Y, int n) {
    constexpr int TN = DOUT / 16;  // 8 for DOUT=128, 4 for DOUT=64
    __shared__ float Xl[128 * 128];
    __shared__ float Wt[DOUT * 128];
    const int t = threadIdx.x;
    const int row0 = blockIdx.x * 128;

    // Stage W^T (swizzled): Wt[c][k ^ ((c>>1)&0x1C)] = W[k][c]
    for (int i = t * 4; i < 128 * DOUT; i += 256 * 4) {
        int k = i / DOUT, c0 = i % DOUT;
        float4 w4 = *(const float4*)(W + i);
        float wv[4] = {w4.x, w4.y, w4.z, w4.w};
#pragma unroll
        for (int j = 0; j < 4; ++j) {
            int c = c0 + j;
            Wt[c * 128 + (k ^ ((c >> 1) & 0x1C))] = wv[j];
        }
    }
    // Stage X tile row-major (swizzled k), zero-padded past n
    for (int i = t * 4; i < 128 * 128; i += 256 * 4) {
        int r = i >> 7;
        int k = i & 127;
        float4 v = {0.f, 0.f, 0.f, 0.f};
        if (row0 + r < n) v = *(const float4*)(X + (size_t)(row0 + r) * 128 + k);
        *(float4*)(Xl + r * 128 + (k ^ ((r >> 1) & 0x1C))) = v;
    }
    __syncthreads();

    const int tm = t & 15;
    const int tn = t >> 4;
    const int xs = (tm & 7) << 2;                  // X swizzle const (rows tm*8+i share it)
    const int ws = (((tn * TN) >> 3) & 7) << 2;    // W swizzle const (cols tn*TN+j share it)

    float acc[8][TN];
#pragma unroll
    for (int i = 0; i < 8; ++i)
#pragma unroll
        for (int j = 0; j < TN; ++j) acc[i][j] = 0.f;

    for (int k4 = 0; k4 < 128; k4 += 4) {
        float4 xv[8], wv[TN];
#pragma unroll
        for (int i = 0; i < 8; ++i)
            xv[i] = *(const float4*)(Xl + (tm * 8 + i) * 128 + (k4 ^ xs));
#pragma unroll
        for (int j = 0; j < TN; ++j)
            wv[j] = *(const float4*)(Wt + (tn * TN + j) * 128 + (k4 ^ ws));
#pragma unroll
        for (int i = 0; i < 8; ++i)
#pragma unroll
            for (int j = 0; j < TN; ++j)
                acc[i][j] += xv[i].x * wv[j].x + xv[i].y * wv[j].y +
                             xv[i].z * wv[j].z + xv[i].w * wv[j].w;
    }

#pragma unroll
    for (int i = 0; i < 8; ++i) {
        int r = row0 + tm * 8 + i;
        if (r < n) {
#pragma unroll
            for (int j = 0; j < TN; j += 4) {
                float4 o = {acc[i][j], acc[i][j + 1], acc[i][j + 2], acc[i][j + 3]};
                *(float4*)(Y + (size_t)r * DOUT + tn * TN + j) = o;
            }
        }
    }
}

// One wave per node. D=128: lane holds 2 dims (float2); D=64: 1 dim.
template <int D>
__global__ __launch_bounds__(256) void prop_kernel(const float* __restrict__ xw,
                                                   const float* __restrict__ dis,
                                                   const int* __restrict__ ptr,
                                                   const int* __restrict__ rows_s,
                                                   const float* __restrict__ ws_s,
                                                   const float* __restrict__ bias,
                                                   float* __restrict__ out,
                                                   int n, int do_relu) {
    const int wid = threadIdx.x >> 6;
    const int lane = threadIdx.x & 63;
    const int v = blockIdx.x * 4 + wid;
    if (v >= n) return;

    const float dv = dis[v];
    const int beg = ptr[v];
    const int end = ptr[v + 1];

    float acc0 = 0.f, acc1 = 0.f;
    for (int base = beg; base < end; base += 64) {
        const int m = end - base;
        int r_l = 0;
        float w_l = 0.f;
        if (lane < m) {
            r_l = rows_s[base + lane];
            w_l = ws_s[base + lane];
        }
        const int lim = m < 64 ? m : 64;
#pragma unroll 4
        for (int j = 0; j < lim; ++j) {
            int r = __shfl(r_l, j);
            float w = __shfl(w_l, j);
            if (D == 128) {
                float2 xv = *(const float2*)(xw + (size_t)r * 128 + lane * 2);
                acc0 += w * xv.x;
                acc1 += w * xv.y;
            } else {
                float xv = xw[(size_t)r * 64 + lane];
                acc0 += w * xv;
            }
        }
    }

    if (D == 128) {
        float2 xv = *(const float2*)(xw + (size_t)v * 128 + lane * 2);
        float r0 = dv * acc0 + dv * dv * xv.x + bias[lane * 2];
        float r1 = dv * acc1 + dv * dv * xv.y + bias[lane * 2 + 1];
        if (do_relu) { r0 = fmaxf(r0, 0.f); r1 = fmaxf(r1, 0.f); }
        float2 o = {r0, r1};
        *(float2*)(out + (size_t)v * 128 + lane * 2) = o;
    } else {
        float xv = xw[(size_t)v * 64 + lane];
        float r0 = dv * acc0 + dv * dv * xv + bias[lane];
        if (do_relu) r0 = fmaxf(r0, 0.f);
        out[(size_t)v * 64 + lane] = r0;
    }
}

extern "C" void kernel_launch(void* const* d_in, const int* in_sizes, int n_in,
                              void* d_out, int out_size, void* d_ws, size_t ws_size,
                              hipStream_t stream) {
    const float* x  = (const float*)d_in[0];
    const void*  ei = d_in[1];
    const float* ew = (const float*)d_in[2];
    const float* W1 = (const float*)d_in[3];
    const float* b1 = (const float*)d_in[4];
    const float* W2 = (const float*)d_in[5];
    const float* b2 = (const float*)d_in[6];
    float* out = (float*)d_out;

    const int n = in_sizes[0] / 128;
    const int E = in_sizes[2];

    char* p = (char*)d_ws;
    size_t o = 0;
    auto alloc = [&](size_t bytes) -> void* {
        void* q = p + o;
        o += (bytes + 255) & ~(size_t)255;
        return q;
    };
    int*   flag   = (int*)alloc(4);
    int*   cnt    = (int*)alloc((size_t)n * 4);
    float* deg    = (float*)alloc((size_t)n * 4);
    int*   ptr    = (int*)alloc(((size_t)n + 1) * 4);
    float* dis    = (float*)alloc((size_t)n * 4);
    int*   rows_s = (int*)alloc((size_t)E * 4);
    float* ws_s   = (float*)alloc((size_t)E * 4);
    float* bufA   = (float*)alloc((size_t)n * 128 * 4);  // xw1, later xw2
    float* bufB   = (float*)alloc((size_t)n * 128 * 4);  // h

    hipMemsetAsync(cnt, 0, (size_t)n * 4, stream);
    hipMemsetAsync(deg, 0, (size_t)n * 4, stream);
    detect_kernel<<<1, 64, 0, stream>>>((const int*)ei, flag);
    count_kernel<<<2048, 256, 0, stream>>>(ei, ew, cnt, deg, E, flag);
    scan_kernel<<<1, 1024, 0, stream>>>(cnt, ptr, n);
    dis_kernel<<<(n + 255) / 256, 256, 0, stream>>>(deg, dis, n);
    hipMemsetAsync(cnt, 0, (size_t)n * 4, stream);
    scatter_kernel<<<2048, 256, 0, stream>>>(ei, ew, dis, ptr, cnt, rows_s, ws_s, E, flag);

    gemm_kernel<128><<<(n + 127) / 128, 256, 0, stream>>>(x, W1, bufA, n);
    prop_kernel<128><<<(n + 3) / 4, 256, 0, stream>>>(bufA, dis, ptr, rows_s, ws_s, b1, bufB, n, 1);
    gemm_kernel<64><<<(n + 127) / 128, 256, 0, stream>>>(bufB, W2, bufA, n);
    prop_kernel<64><<<(n + 3) / 4, 256, 0, stream>>>(bufA, dis, ptr, rows_s, ws_s, b2, out, n, 0);
}

// Round 3
// 679.166 us; speedup vs baseline: 1.2472x; 1.2185x over previous
//
#include <hip/hip_runtime.h>
#include <stdint.h>

// ---------------------------------------------------------------------------
// GCN 2-layer: out = GCNConv(relu(GCNConv(x, W1,b1)), W2,b2)
// deg[c] = sum ew over edges into c (col is destination), dis = rsqrt(deg+1)
// agg[c] = dis[c] * sum_e( dis[row_e]*ew_e * xw[row_e] ) + dis[c]^2 * xw[c]
// ---------------------------------------------------------------------------

// Detect int64 vs int32 edge_index layout: int64 little-endian values < 2^31
// have zero hi-words at every odd int32 slot.
__global__ void detect_kernel(const int* __restrict__ ei, int* flag) {
    if (threadIdx.x == 0 && blockIdx.x == 0) {
        int z = 0;
        for (int i = 0; i < 16; ++i) z |= ei[2 * i + 1];
        *flag = (z == 0) ? 1 : 0;
    }
}

__global__ void count_kernel(const void* __restrict__ ei, const float* __restrict__ ew,
                             int* __restrict__ cnt, float* __restrict__ deg,
                             int E, const int* __restrict__ flag) {
    const int is64 = *flag;
    const int* e32 = (const int*)ei;
    const long long* e64 = (const long long*)ei;
    for (int e = blockIdx.x * blockDim.x + threadIdx.x; e < E;
         e += gridDim.x * blockDim.x) {
        int c = is64 ? (int)e64[(size_t)E + e] : e32[(size_t)E + e];
        atomicAdd(&cnt[c], 1);
        atomicAdd(&deg[c], ew[e]);
    }
}

// ---------------------------------------------------------------------------
// 3-phase multi-block exclusive scan over cnt[0..n) -> ptr[0..n].
// CHUNK=4096 elements/block (4/thread via int4). Phase A: block sums.
// Phase B: 1-block exclusive scan of block sums (<=1024 blocks).
// Phase C: per-block scan + global offset, writes ptr (and ptr[n]).
// ---------------------------------------------------------------------------
__global__ __launch_bounds__(1024) void scanA_kernel(const int* __restrict__ cnt,
                                                     int* __restrict__ bsum, int n) {
    __shared__ int sm[1024];
    const int t = threadIdx.x;
    const int base = blockIdx.x * 4096 + t * 4;
    int s = 0;
    if (base + 3 < n) {
        int4 v = *(const int4*)(cnt + base);
        s = v.x + v.y + v.z + v.w;
    } else {
        for (int i = 0; i < 4; ++i) if (base + i < n) s += cnt[base + i];
    }
    sm[t] = s;
    __syncthreads();
    for (int off = 512; off > 0; off >>= 1) {
        if (t < off) sm[t] += sm[t + off];
        __syncthreads();
    }
    if (t == 0) bsum[blockIdx.x] = sm[0];
}

__global__ __launch_bounds__(1024) void scanB_kernel(int* __restrict__ bsum, int nb) {
    __shared__ int sm[1024];
    const int t = threadIdx.x;
    sm[t] = (t < nb) ? bsum[t] : 0;
    __syncthreads();
    for (int off = 1; off < 1024; off <<= 1) {
        int v = (t >= off) ? sm[t - off] : 0;
        __syncthreads();
        sm[t] += v;
        __syncthreads();
    }
    if (t < nb) bsum[t] = (t == 0) ? 0 : sm[t - 1];  // exclusive
}

__global__ __launch_bounds__(1024) void scanC_kernel(const int* __restrict__ cnt,
                                                     const int* __restrict__ bsum,
                                                     int* __restrict__ ptr, int n, int nb) {
    __shared__ int sm[1024];
    const int t = threadIdx.x;
    const int base = blockIdx.x * 4096 + t * 4;
    int v0 = 0, v1 = 0, v2 = 0, v3 = 0;
    if (base + 3 < n) {
        int4 v = *(const int4*)(cnt + base);
        v0 = v.x; v1 = v.y; v2 = v.z; v3 = v.w;
    } else {
        if (base + 0 < n) v0 = cnt[base + 0];
        if (base + 1 < n) v1 = cnt[base + 1];
        if (base + 2 < n) v2 = cnt[base + 2];
        if (base + 3 < n) v3 = cnt[base + 3];
    }
    int s = v0 + v1 + v2 + v3;
    sm[t] = s;
    __syncthreads();
    for (int off = 1; off < 1024; off <<= 1) {
        int v = (t >= off) ? sm[t - off] : 0;
        __syncthreads();
        sm[t] += v;
        __syncthreads();
    }
    int run = bsum[blockIdx.x] + ((t == 0) ? 0 : sm[t - 1]);
    if (base + 0 < n) ptr[base + 0] = run;
    run += v0;
    if (base + 1 < n) ptr[base + 1] = run;
    run += v1;
    if (base + 2 < n) ptr[base + 2] = run;
    run += v2;
    if (base + 3 < n) ptr[base + 3] = run;
    run += v3;
    if (base <= n && base + 4 > n) ptr[n] = run;  // thread covering the tail writes total
}

__global__ void dis_kernel(const float* __restrict__ deg, float* __restrict__ dis, int n) {
    int i = blockIdx.x * blockDim.x + threadIdx.x;
    if (i < n) dis[i] = rsqrtf(deg[i] + 1.0f);
}

__global__ void scatter_kernel(const void* __restrict__ ei, const float* __restrict__ ew,
                               const float* __restrict__ dis, const int* __restrict__ ptr,
                               int* __restrict__ cur, int* __restrict__ rows_s,
                               float* __restrict__ ws_s, int E, const int* __restrict__ flag) {
    const int is64 = *flag;
    const int* e32 = (const int*)ei;
    const long long* e64 = (const long long*)ei;
    for (int e = blockIdx.x * blockDim.x + threadIdx.x; e < E;
         e += gridDim.x * blockDim.x) {
        int r, c;
        if (is64) { r = (int)e64[e]; c = (int)e64[(size_t)E + e]; }
        else      { r = e32[e];      c = e32[(size_t)E + e]; }
        int pos = ptr[c] + atomicAdd(&cur[c], 1);
        rows_s[pos] = r;
        ws_s[pos] = dis[r] * ew[e];
    }
}

// ---------------------------------------------------------------------------
// Y[n,DOUT] = X[n,128] @ W[128,DOUT], fp32 vector-ALU GEMM.
// 256 threads, BM=128 rows, full K=128 staged once (no barriers in main loop).
// Xl[m][k] row-major + XOR bank-swizzle on k; Wt[n][k] = W^T, same swizzle.
// Thread (tm=t&15, tn=t>>4) computes rows tm*8..+8, cols tn*TN..+TN (TN=DOUT/16).
// ---------------------------------------------------------------------------
template <int DOUT>
__global__ __launch_bounds__(256) void gemm_kernel(const float* __restrict__ X,
                                                   const float* __restrict__ W,
                                                   float* __restrict__ Y, int n) {
    constexpr int TN = DOUT / 16;  // 8 for DOUT=128, 4 for DOUT=64
    __shared__ float Xl[128 * 128];
    __shared__ float Wt[DOUT * 128];
    const int t = threadIdx.x;
    const int row0 = blockIdx.x * 128;

    // Stage W^T (swizzled): Wt[c][k ^ ((c>>1)&0x1C)] = W[k][c]
    for (int i = t * 4; i < 128 * DOUT; i += 256 * 4) {
        int k = i / DOUT, c0 = i % DOUT;
        float4 w4 = *(const float4*)(W + i);
        float wv[4] = {w4.x, w4.y, w4.z, w4.w};
#pragma unroll
        for (int j = 0; j < 4; ++j) {
            int c = c0 + j;
            Wt[c * 128 + (k ^ ((c >> 1) & 0x1C))] = wv[j];
        }
    }
    // Stage X tile row-major (swizzled k), zero-padded past n
    for (int i = t * 4; i < 128 * 128; i += 256 * 4) {
        int r = i >> 7;
        int k = i & 127;
        float4 v = {0.f, 0.f, 0.f, 0.f};
        if (row0 + r < n) v = *(const float4*)(X + (size_t)(row0 + r) * 128 + k);
        *(float4*)(Xl + r * 128 + (k ^ ((r >> 1) & 0x1C))) = v;
    }
    __syncthreads();

    const int tm = t & 15;
    const int tn = t >> 4;
    const int xs = (tm & 7) << 2;                  // X swizzle const
    const int ws = (((tn * TN) >> 3) & 7) << 2;    // W swizzle const

    float acc[8][TN];
#pragma unroll
    for (int i = 0; i < 8; ++i)
#pragma unroll
        for (int j = 0; j < TN; ++j) acc[i][j] = 0.f;

    for (int k4 = 0; k4 < 128; k4 += 4) {
        float4 xv[8], wv[TN];
#pragma unroll
        for (int i = 0; i < 8; ++i)
            xv[i] = *(const float4*)(Xl + (tm * 8 + i) * 128 + (k4 ^ xs));
#pragma unroll
        for (int j = 0; j < TN; ++j)
            wv[j] = *(const float4*)(Wt + (tn * TN + j) * 128 + (k4 ^ ws));
#pragma unroll
        for (int i = 0; i < 8; ++i)
#pragma unroll
            for (int j = 0; j < TN; ++j)
                acc[i][j] += xv[i].x * wv[j].x + xv[i].y * wv[j].y +
                             xv[i].z * wv[j].z + xv[i].w * wv[j].w;
    }

#pragma unroll
    for (int i = 0; i < 8; ++i) {
        int r = row0 + tm * 8 + i;
        if (r < n) {
#pragma unroll
            for (int j = 0; j < TN; j += 4) {
                float4 o = {acc[i][j], acc[i][j + 1], acc[i][j + 2], acc[i][j + 3]};
                *(float4*)(Y + (size_t)r * DOUT + tn * TN + j) = o;
            }
        }
    }
}

// One wave per node. D=128: lane holds 2 dims (float2); D=64: 1 dim.
template <int D>
__global__ __launch_bounds__(256) void prop_kernel(const float* __restrict__ xw,
                                                   const float* __restrict__ dis,
                                                   const int* __restrict__ ptr,
                                                   const int* __restrict__ rows_s,
                                                   const float* __restrict__ ws_s,
                                                   const float* __restrict__ bias,
                                                   float* __restrict__ out,
                                                   int n, int do_relu) {
    const int wid = threadIdx.x >> 6;
    const int lane = threadIdx.x & 63;
    const int v = blockIdx.x * 4 + wid;
    if (v >= n) return;

    const float dv = dis[v];
    const int beg = ptr[v];
    const int end = ptr[v + 1];

    float acc0 = 0.f, acc1 = 0.f;
    for (int base = beg; base < end; base += 64) {
        const int m = end - base;
        int r_l = 0;
        float w_l = 0.f;
        if (lane < m) {
            r_l = rows_s[base + lane];
            w_l = ws_s[base + lane];
        }
        const int lim = m < 64 ? m : 64;
#pragma unroll 4
        for (int j = 0; j < lim; ++j) {
            int r = __shfl(r_l, j);
            float w = __shfl(w_l, j);
            if (D == 128) {
                float2 xv = *(const float2*)(xw + (size_t)r * 128 + lane * 2);
                acc0 += w * xv.x;
                acc1 += w * xv.y;
            } else {
                float xv = xw[(size_t)r * 64 + lane];
                acc0 += w * xv;
            }
        }
    }

    if (D == 128) {
        float2 xv = *(const float2*)(xw + (size_t)v * 128 + lane * 2);
        float r0 = dv * acc0 + dv * dv * xv.x + bias[lane * 2];
        float r1 = dv * acc1 + dv * dv * xv.y + bias[lane * 2 + 1];
        if (do_relu) { r0 = fmaxf(r0, 0.f); r1 = fmaxf(r1, 0.f); }
        float2 o = {r0, r1};
        *(float2*)(out + (size_t)v * 128 + lane * 2) = o;
    } else {
        float xv = xw[(size_t)v * 64 + lane];
        float r0 = dv * acc0 + dv * dv * xv + bias[lane];
        if (do_relu) r0 = fmaxf(r0, 0.f);
        out[(size_t)v * 64 + lane] = r0;
    }
}

extern "C" void kernel_launch(void* const* d_in, const int* in_sizes, int n_in,
                              void* d_out, int out_size, void* d_ws, size_t ws_size,
                              hipStream_t stream) {
    const float* x  = (const float*)d_in[0];
    const void*  ei = d_in[1];
    const float* ew = (const float*)d_in[2];
    const float* W1 = (const float*)d_in[3];
    const float* b1 = (const float*)d_in[4];
    const float* W2 = (const float*)d_in[5];
    const float* b2 = (const float*)d_in[6];
    float* out = (float*)d_out;

    const int n = in_sizes[0] / 128;
    const int E = in_sizes[2];

    char* p = (char*)d_ws;
    size_t o = 0;
    auto alloc = [&](size_t bytes) -> void* {
        void* q = p + o;
        o += (bytes + 255) & ~(size_t)255;
        return q;
    };
    int*   flag   = (int*)alloc(4);
    int*   cnt    = (int*)alloc((size_t)n * 4);
    float* deg    = (float*)alloc((size_t)n * 4);
    int*   ptr    = (int*)alloc(((size_t)n + 1) * 4);
    int*   bsum   = (int*)alloc(1024 * 4);
    float* dis    = (float*)alloc((size_t)n * 4);
    int*   rows_s = (int*)alloc((size_t)E * 4);
    float* ws_s   = (float*)alloc((size_t)E * 4);
    float* bufA   = (float*)alloc((size_t)n * 128 * 4);  // xw1, later xw2
    float* bufB   = (float*)alloc((size_t)n * 128 * 4);  // h

    const int nb = (n + 4095) / 4096;  // scan blocks (<=1024 supported)

    hipMemsetAsync(cnt, 0, (size_t)n * 4, stream);
    hipMemsetAsync(deg, 0, (size_t)n * 4, stream);
    detect_kernel<<<1, 64, 0, stream>>>((const int*)ei, flag);
    count_kernel<<<2048, 256, 0, stream>>>(ei, ew, cnt, deg, E, flag);
    scanA_kernel<<<nb, 1024, 0, stream>>>(cnt, bsum, n);
    scanB_kernel<<<1, 1024, 0, stream>>>(bsum, nb);
    scanC_kernel<<<nb, 1024, 0, stream>>>(cnt, bsum, ptr, n, nb);
    dis_kernel<<<(n + 255) / 256, 256, 0, stream>>>(deg, dis, n);
    hipMemsetAsync(cnt, 0, (size_t)n * 4, stream);
    scatter_kernel<<<2048, 256, 0, stream>>>(ei, ew, dis, ptr, cnt, rows_s, ws_s, E, flag);

    gemm_kernel<128><<<(n + 127) / 128, 256, 0, stream>>>(x, W1, bufA, n);
    prop_kernel<128><<<(n + 3) / 4, 256, 0, stream>>>(bufA, dis, ptr, rows_s, ws_s, b1, bufB, n, 1);
    gemm_kernel<64><<<(n + 127) / 128, 256, 0, stream>>>(bufB, W2, bufA, n);
    prop_kernel<64><<<(n + 3) / 4, 256, 0, stream>>>(bufA, dis, ptr, rows_s, ws_s, b2, out, n, 0);
}

// Round 4
// 566.986 us; speedup vs baseline: 1.4940x; 1.1979x over previous
//
#include <hip/hip_runtime.h>
#include <stdint.h>

// ---------------------------------------------------------------------------
// GCN 2-layer: out = GCNConv(relu(GCNConv(x, W1,b1)), W2,b2)
// deg[c] = sum ew over edges into c, dis = rsqrt(deg+1)
// agg[c] = dis[c] * sum_e( dis[row_e]*ew_e * xw[row_e] ) + dis[c]^2 * xw[c]
// ---------------------------------------------------------------------------

__global__ void detect_kernel(const int* __restrict__ ei, int* flag) {
    if (threadIdx.x == 0 && blockIdx.x == 0) {
        int z = 0;
        for (int i = 0; i < 16; ++i) z |= ei[2 * i + 1];
        *flag = (z == 0) ? 1 : 0;
    }
}

// One int atomic per edge (deg is computed atomic-free later from CSR).
__global__ void count_kernel(const void* __restrict__ ei,
                             int* __restrict__ cnt,
                             int E, const int* __restrict__ flag) {
    const int is64 = *flag;
    const int* e32 = (const int*)ei;
    const long long* e64 = (const long long*)ei;
    for (int e = blockIdx.x * blockDim.x + threadIdx.x; e < E;
         e += gridDim.x * blockDim.x) {
        int c = is64 ? (int)e64[(size_t)E + e] : e32[(size_t)E + e];
        atomicAdd(&cnt[c], 1);
    }
}

// ---------------------------------------------------------------------------
// 3-phase multi-block exclusive scan over cnt[0..n) -> ptr[0..n].
// ---------------------------------------------------------------------------
__global__ __launch_bounds__(1024) void scanA_kernel(const int* __restrict__ cnt,
                                                     int* __restrict__ bsum, int n) {
    __shared__ int sm[1024];
    const int t = threadIdx.x;
    const int base = blockIdx.x * 4096 + t * 4;
    int s = 0;
    if (base + 3 < n) {
        int4 v = *(const int4*)(cnt + base);
        s = v.x + v.y + v.z + v.w;
    } else {
        for (int i = 0; i < 4; ++i) if (base + i < n) s += cnt[base + i];
    }
    sm[t] = s;
    __syncthreads();
    for (int off = 512; off > 0; off >>= 1) {
        if (t < off) sm[t] += sm[t + off];
        __syncthreads();
    }
    if (t == 0) bsum[blockIdx.x] = sm[0];
}

__global__ __launch_bounds__(1024) void scanB_kernel(int* __restrict__ bsum, int nb) {
    __shared__ int sm[1024];
    const int t = threadIdx.x;
    sm[t] = (t < nb) ? bsum[t] : 0;
    __syncthreads();
    for (int off = 1; off < 1024; off <<= 1) {
        int v = (t >= off) ? sm[t - off] : 0;
        __syncthreads();
        sm[t] += v;
        __syncthreads();
    }
    if (t < nb) bsum[t] = (t == 0) ? 0 : sm[t - 1];  // exclusive
}

__global__ __launch_bounds__(1024) void scanC_kernel(const int* __restrict__ cnt,
                                                     const int* __restrict__ bsum,
                                                     int* __restrict__ ptr, int n, int nb) {
    __shared__ int sm[1024];
    const int t = threadIdx.x;
    const int base = blockIdx.x * 4096 + t * 4;
    int v0 = 0, v1 = 0, v2 = 0, v3 = 0;
    if (base + 3 < n) {
        int4 v = *(const int4*)(cnt + base);
        v0 = v.x; v1 = v.y; v2 = v.z; v3 = v.w;
    } else {
        if (base + 0 < n) v0 = cnt[base + 0];
        if (base + 1 < n) v1 = cnt[base + 1];
        if (base + 2 < n) v2 = cnt[base + 2];
        if (base + 3 < n) v3 = cnt[base + 3];
    }
    int s = v0 + v1 + v2 + v3;
    sm[t] = s;
    __syncthreads();
    for (int off = 1; off < 1024; off <<= 1) {
        int v = (t >= off) ? sm[t - off] : 0;
        __syncthreads();
        sm[t] += v;
        __syncthreads();
    }
    int run = bsum[blockIdx.x] + ((t == 0) ? 0 : sm[t - 1]);
    if (base + 0 < n) ptr[base + 0] = run;
    run += v0;
    if (base + 1 < n) ptr[base + 1] = run;
    run += v1;
    if (base + 2 < n) ptr[base + 2] = run;
    run += v2;
    if (base + 3 < n) ptr[base + 3] = run;
    run += v3;
    if (base <= n && base + 4 > n) ptr[n] = run;
}

// Scatter edges to CSR-by-destination; store raw ew (dis applied in prop).
__global__ void scatter_kernel(const void* __restrict__ ei, const float* __restrict__ ew,
                               const int* __restrict__ ptr,
                               int* __restrict__ cur, int* __restrict__ rows_s,
                               float* __restrict__ ws_s, int E, const int* __restrict__ flag) {
    const int is64 = *flag;
    const int* e32 = (const int*)ei;
    const long long* e64 = (const long long*)ei;
    for (int e = blockIdx.x * blockDim.x + threadIdx.x; e < E;
         e += gridDim.x * blockDim.x) {
        int r, c;
        if (is64) { r = (int)e64[e]; c = (int)e64[(size_t)E + e]; }
        else      { r = e32[e];      c = e32[(size_t)E + e]; }
        int pos = ptr[c] + atomicAdd(&cur[c], 1);
        rows_s[pos] = r;
        ws_s[pos] = ew[e];
    }
}

// deg[v] = sum of scattered raw ew over v's CSR segment; dis = rsqrt(deg+1).
__global__ void degdis_kernel(const int* __restrict__ ptr, const float* __restrict__ ws_s,
                              float* __restrict__ dis, int n) {
    int v = blockIdx.x * blockDim.x + threadIdx.x;
    if (v >= n) return;
    float s = 0.f;
    const int e1 = ptr[v + 1];
    for (int e = ptr[v]; e < e1; ++e) s += ws_s[e];
    dis[v] = rsqrtf(s + 1.0f);
}

// ---------------------------------------------------------------------------
// Y[n,DOUT] = X[n,128] @ W[128,DOUT], fp32 vector-ALU GEMM.
// 512 threads, BM=128 rows, K staged in two 64-wide halves (LDS = 64/48 KB ->
// 2 blocks/CU, 4 waves/SIMD). XOR swizzle ((row>>3)&7)<<2 on k keeps compute
// reads <=2-way (free). Thread (tm=t&15, tn=t>>4): rows tm*8..+8, cols
// tn*TN..+TN, TN=DOUT/32.
// ---------------------------------------------------------------------------
template <int DOUT>
__global__ __launch_bounds__(512, 4) void gemm_kernel(const float* __restrict__ X,
                                                      const float* __restrict__ W,
                                                      float* __restrict__ Y, int n) {
    constexpr int TN = DOUT / 32;  // 4 for DOUT=128, 2 for DOUT=64
    __shared__ float Xl[128 * 64];
    __shared__ float Wt[DOUT * 64];
    const int t = threadIdx.x;
    const int row0 = blockIdx.x * 128;
    const int tm = t & 15;
    const int tn = t >> 4;
    const int xs = (tm & 7) << 2;
    const int ws = (((tn * TN) >> 3) & 7) << 2;

    float acc[8][TN];
#pragma unroll
    for (int i = 0; i < 8; ++i)
#pragma unroll
        for (int j = 0; j < TN; ++j) acc[i][j] = 0.f;

    for (int h = 0; h < 2; ++h) {
        const int k0 = h * 64;
        // Stage X half-tile (swizzled k), zero-padded past n
        for (int i = t * 4; i < 128 * 64; i += 512 * 4) {
            int r = i >> 6, kk = i & 63;
            float4 v = {0.f, 0.f, 0.f, 0.f};
            if (row0 + r < n) v = *(const float4*)(X + (size_t)(row0 + r) * 128 + k0 + kk);
            *(float4*)(Xl + r * 64 + (kk ^ (((r >> 3) & 7) << 2))) = v;
        }
        // Stage W^T half: Wt[c][kk ^ swz(c)] = W[k0+kk][c]
        for (int i = t * 4; i < 64 * DOUT; i += 512 * 4) {
            int kk = i / DOUT, c0 = i % DOUT;
            float4 w4 = *(const float4*)(W + (size_t)(k0 + kk) * DOUT + c0);
            float wvv[4] = {w4.x, w4.y, w4.z, w4.w};
#pragma unroll
            for (int j = 0; j < 4; ++j) {
                int c = c0 + j;
                Wt[c * 64 + (kk ^ (((c >> 3) & 7) << 2))] = wvv[j];
            }
        }
        __syncthreads();

        for (int k4 = 0; k4 < 64; k4 += 4) {
            float4 xv[8], wv[TN];
#pragma unroll
            for (int i = 0; i < 8; ++i)
                xv[i] = *(const float4*)(Xl + (tm * 8 + i) * 64 + (k4 ^ xs));
#pragma unroll
            for (int j = 0; j < TN; ++j)
                wv[j] = *(const float4*)(Wt + (tn * TN + j) * 64 + (k4 ^ ws));
#pragma unroll
            for (int i = 0; i < 8; ++i)
#pragma unroll
                for (int j = 0; j < TN; ++j)
                    acc[i][j] += xv[i].x * wv[j].x + xv[i].y * wv[j].y +
                                 xv[i].z * wv[j].z + xv[i].w * wv[j].w;
        }
        __syncthreads();
    }

#pragma unroll
    for (int i = 0; i < 8; ++i) {
        int r = row0 + tm * 8 + i;
        if (r < n) {
            if (TN == 4) {
                float4 o = {acc[i][0], acc[i][1], acc[i][2], acc[i][3]};
                *(float4*)(Y + (size_t)r * DOUT + tn * TN) = o;
            } else {
                float2 o = {acc[i][0], acc[i][1]};
                *(float2*)(Y + (size_t)r * DOUT + tn * TN) = o;
            }
        }
    }
}

// One wave per node. D=128: lane holds 2 dims (float2); D=64: 1 dim.
// dis[row] gathered inline (L2-resident 400 KB table).
template <int D>
__global__ __launch_bounds__(256) void prop_kernel(const float* __restrict__ xw,
                                                   const float* __restrict__ dis,
                                                   const int* __restrict__ ptr,
                                                   const int* __restrict__ rows_s,
                                                   const float* __restrict__ ws_s,
                                                   const float* __restrict__ bias,
                                                   float* __restrict__ out,
                                                   int n, int do_relu) {
    const int wid = threadIdx.x >> 6;
    const int lane = threadIdx.x & 63;
    const int v = blockIdx.x * 4 + wid;
    if (v >= n) return;

    const float dv = dis[v];
    const int beg = ptr[v];
    const int end = ptr[v + 1];

    float acc0 = 0.f, acc1 = 0.f;
    for (int base = beg; base < end; base += 64) {
        const int m = end - base;
        int r_l = 0;
        float w_l = 0.f;
        if (lane < m) {
            r_l = rows_s[base + lane];
            w_l = ws_s[base + lane] * dis[r_l];
        }
        const int lim = m < 64 ? m : 64;
#pragma unroll 4
        for (int j = 0; j < lim; ++j) {
            int r = __shfl(r_l, j);
            float w = __shfl(w_l, j);
            if (D == 128) {
                float2 xv = *(const float2*)(xw + (size_t)r * 128 + lane * 2);
                acc0 += w * xv.x;
                acc1 += w * xv.y;
            } else {
                float xv = xw[(size_t)r * 64 + lane];
                acc0 += w * xv;
            }
        }
    }

    if (D == 128) {
        float2 xv = *(const float2*)(xw + (size_t)v * 128 + lane * 2);
        float r0 = dv * acc0 + dv * dv * xv.x + bias[lane * 2];
        float r1 = dv * acc1 + dv * dv * xv.y + bias[lane * 2 + 1];
        if (do_relu) { r0 = fmaxf(r0, 0.f); r1 = fmaxf(r1, 0.f); }
        float2 o = {r0, r1};
        *(float2*)(out + (size_t)v * 128 + lane * 2) = o;
    } else {
        float xv = xw[(size_t)v * 64 + lane];
        float r0 = dv * acc0 + dv * dv * xv + bias[lane];
        if (do_relu) r0 = fmaxf(r0, 0.f);
        out[(size_t)v * 64 + lane] = r0;
    }
}

extern "C" void kernel_launch(void* const* d_in, const int* in_sizes, int n_in,
                              void* d_out, int out_size, void* d_ws, size_t ws_size,
                              hipStream_t stream) {
    const float* x  = (const float*)d_in[0];
    const void*  ei = d_in[1];
    const float* ew = (const float*)d_in[2];
    const float* W1 = (const float*)d_in[3];
    const float* b1 = (const float*)d_in[4];
    const float* W2 = (const float*)d_in[5];
    const float* b2 = (const float*)d_in[6];
    float* out = (float*)d_out;

    const int n = in_sizes[0] / 128;
    const int E = in_sizes[2];

    char* p = (char*)d_ws;
    size_t o = 0;
    auto alloc = [&](size_t bytes) -> void* {
        void* q = p + o;
        o += (bytes + 255) & ~(size_t)255;
        return q;
    };
    int*   flag   = (int*)alloc(4);
    int*   cnt    = (int*)alloc((size_t)n * 4);
    int*   ptr    = (int*)alloc(((size_t)n + 1) * 4);
    int*   bsum   = (int*)alloc(1024 * 4);
    float* dis    = (float*)alloc((size_t)n * 4);
    int*   rows_s = (int*)alloc((size_t)E * 4);
    float* ws_s   = (float*)alloc((size_t)E * 4);
    float* bufA   = (float*)alloc((size_t)n * 128 * 4);  // xw1, later xw2
    float* bufB   = (float*)alloc((size_t)n * 128 * 4);  // h

    const int nb = (n + 4095) / 4096;  // scan blocks (<=1024 supported)

    hipMemsetAsync(cnt, 0, (size_t)n * 4, stream);
    detect_kernel<<<1, 64, 0, stream>>>((const int*)ei, flag);
    count_kernel<<<2048, 256, 0, stream>>>(ei, cnt, E, flag);
    scanA_kernel<<<nb, 1024, 0, stream>>>(cnt, bsum, n);
    scanB_kernel<<<1, 1024, 0, stream>>>(bsum, nb);
    scanC_kernel<<<nb, 1024, 0, stream>>>(cnt, bsum, ptr, n, nb);
    hipMemsetAsync(cnt, 0, (size_t)n * 4, stream);
    scatter_kernel<<<2048, 256, 0, stream>>>(ei, ew, ptr, cnt, rows_s, ws_s, E, flag);
    degdis_kernel<<<(n + 255) / 256, 256, 0, stream>>>(ptr, ws_s, dis, n);

    gemm_kernel<128><<<(n + 127) / 128, 512, 0, stream>>>(x, W1, bufA, n);
    prop_kernel<128><<<(n + 3) / 4, 256, 0, stream>>>(bufA, dis, ptr, rows_s, ws_s, b1, bufB, n, 1);
    gemm_kernel<64><<<(n + 127) / 128, 512, 0, stream>>>(bufB, W2, bufA, n);
    prop_kernel<64><<<(n + 3) / 4, 256, 0, stream>>>(bufA, dis, ptr, rows_s, ws_s, b2, out, n, 0);
}

// Round 5
// 420.222 us; speedup vs baseline: 2.0158x; 1.3493x over previous
//
#include <hip/hip_runtime.h>
#include <stdint.h>

typedef unsigned int uint32;

// ---------------------------------------------------------------------------
// GCN 2-layer: out = GCNConv(relu(GCNConv(x, W1,b1)), W2,b2)
// deg[c] = sum ew into c, dis = rsqrt(deg+1)
// agg[c] = dis[c] * sum_e( dis[row_e]*ew_e * xw[row_e] ) + dis[c]^2 * xw[c]
// xw staged as packed bf16x2 for the gather phase (halves gather traffic).
// ---------------------------------------------------------------------------

__global__ void detect_kernel(const int* __restrict__ ei, int* flag) {
    if (threadIdx.x == 0 && blockIdx.x == 0) {
        int z = 0;
        for (int i = 0; i < 16; ++i) z |= ei[2 * i + 1];
        *flag = (z == 0) ? 1 : 0;
    }
}

// Counting pass; the returned old value IS the edge's rank within its node
// segment (ticket). Scatter later needs no atomics.
__global__ void count_kernel(const void* __restrict__ ei,
                             int* __restrict__ cnt, int* __restrict__ tick,
                             int E, const int* __restrict__ flag) {
    const int is64 = *flag;
    const int* e32 = (const int*)ei;
    const long long* e64 = (const long long*)ei;
    for (int e = blockIdx.x * blockDim.x + threadIdx.x; e < E;
         e += gridDim.x * blockDim.x) {
        int c = is64 ? (int)e64[(size_t)E + e] : e32[(size_t)E + e];
        tick[e] = atomicAdd(&cnt[c], 1);
    }
}

// ---------------------------------------------------------------------------
// 3-phase multi-block exclusive scan over cnt[0..n) -> ptr[0..n].
// ---------------------------------------------------------------------------
__global__ __launch_bounds__(1024) void scanA_kernel(const int* __restrict__ cnt,
                                                     int* __restrict__ bsum, int n) {
    __shared__ int sm[1024];
    const int t = threadIdx.x;
    const int base = blockIdx.x * 4096 + t * 4;
    int s = 0;
    if (base + 3 < n) {
        int4 v = *(const int4*)(cnt + base);
        s = v.x + v.y + v.z + v.w;
    } else {
        for (int i = 0; i < 4; ++i) if (base + i < n) s += cnt[base + i];
    }
    sm[t] = s;
    __syncthreads();
    for (int off = 512; off > 0; off >>= 1) {
        if (t < off) sm[t] += sm[t + off];
        __syncthreads();
    }
    if (t == 0) bsum[blockIdx.x] = sm[0];
}

__global__ __launch_bounds__(1024) void scanB_kernel(int* __restrict__ bsum, int nb) {
    __shared__ int sm[1024];
    const int t = threadIdx.x;
    sm[t] = (t < nb) ? bsum[t] : 0;
    __syncthreads();
    for (int off = 1; off < 1024; off <<= 1) {
        int v = (t >= off) ? sm[t - off] : 0;
        __syncthreads();
        sm[t] += v;
        __syncthreads();
    }
    if (t < nb) bsum[t] = (t == 0) ? 0 : sm[t - 1];  // exclusive
}

__global__ __launch_bounds__(1024) void scanC_kernel(const int* __restrict__ cnt,
                                                     const int* __restrict__ bsum,
                                                     int* __restrict__ ptr, int n, int nb) {
    __shared__ int sm[1024];
    const int t = threadIdx.x;
    const int base = blockIdx.x * 4096 + t * 4;
    int v0 = 0, v1 = 0, v2 = 0, v3 = 0;
    if (base + 3 < n) {
        int4 v = *(const int4*)(cnt + base);
        v0 = v.x; v1 = v.y; v2 = v.z; v3 = v.w;
    } else {
        if (base + 0 < n) v0 = cnt[base + 0];
        if (base + 1 < n) v1 = cnt[base + 1];
        if (base + 2 < n) v2 = cnt[base + 2];
        if (base + 3 < n) v3 = cnt[base + 3];
    }
    int s = v0 + v1 + v2 + v3;
    sm[t] = s;
    __syncthreads();
    for (int off = 1; off < 1024; off <<= 1) {
        int v = (t >= off) ? sm[t - off] : 0;
        __syncthreads();
        sm[t] += v;
        __syncthreads();
    }
    int run = bsum[blockIdx.x] + ((t == 0) ? 0 : sm[t - 1]);
    if (base + 0 < n) ptr[base + 0] = run;
    run += v0;
    if (base + 1 < n) ptr[base + 1] = run;
    run += v1;
    if (base + 2 < n) ptr[base + 2] = run;
    run += v2;
    if (base + 3 < n) ptr[base + 3] = run;
    run += v3;
    if (base <= n && base + 4 > n) ptr[n] = run;
}

// Atomic-free scatter: pos = ptr[c] + tick[e]; one 8B record {row, ew_bits}.
__global__ void scatter_kernel(const void* __restrict__ ei, const float* __restrict__ ew,
                               const int* __restrict__ ptr, const int* __restrict__ tick,
                               int2* __restrict__ rec, int E, const int* __restrict__ flag) {
    const int is64 = *flag;
    const int* e32 = (const int*)ei;
    const long long* e64 = (const long long*)ei;
    for (int e = blockIdx.x * blockDim.x + threadIdx.x; e < E;
         e += gridDim.x * blockDim.x) {
        int r, c;
        if (is64) { r = (int)e64[e]; c = (int)e64[(size_t)E + e]; }
        else      { r = e32[e];      c = e32[(size_t)E + e]; }
        int pos = ptr[c] + tick[e];
        rec[pos] = make_int2(r, __float_as_int(ew[e]));
    }
}

// deg[v] = sum of record weights over v's CSR segment; dis = rsqrt(deg+1).
__global__ void degdis_kernel(const int* __restrict__ ptr, const int2* __restrict__ rec,
                              float* __restrict__ dis, int n) {
    int v = blockIdx.x * blockDim.x + threadIdx.x;
    if (v >= n) return;
    float s = 0.f;
    const int e1 = ptr[v + 1];
    for (int e = ptr[v]; e < e1; ++e) s += __int_as_float(rec[e].y);
    dis[v] = rsqrtf(s + 1.0f);
}

__device__ inline uint32 bf16rne(float f) {
    uint32 u = __float_as_uint(f);
    u += 0x7FFF + ((u >> 16) & 1);
    return u >> 16;
}
__device__ inline uint32 pack2(float a, float b) { return bf16rne(a) | (bf16rne(b) << 16); }
__device__ inline float bflo(uint32 g) { return __uint_as_float(g << 16); }
__device__ inline float bfhi(uint32 g) { return __uint_as_float(g & 0xFFFF0000u); }

// ---------------------------------------------------------------------------
// Y[n,DOUT] = X[n,128] @ W[128,DOUT], fp32 vector-ALU GEMM, bf16x2-packed out.
// 512 threads, BM=128 rows, K staged in two 64-wide halves (2 blocks/CU).
// ---------------------------------------------------------------------------
template <int DOUT>
__global__ __launch_bounds__(512, 4) void gemm_kernel(const float* __restrict__ X,
                                                      const float* __restrict__ W,
                                                      uint32* __restrict__ Y, int n) {
    constexpr int TN = DOUT / 32;  // 4 for DOUT=128, 2 for DOUT=64
    __shared__ float Xl[128 * 64];
    __shared__ float Wt[DOUT * 64];
    const int t = threadIdx.x;
    const int row0 = blockIdx.x * 128;
    const int tm = t & 15;
    const int tn = t >> 4;
    const int xs = (tm & 7) << 2;
    const int ws = (((tn * TN) >> 3) & 7) << 2;

    float acc[8][TN];
#pragma unroll
    for (int i = 0; i < 8; ++i)
#pragma unroll
        for (int j = 0; j < TN; ++j) acc[i][j] = 0.f;

    for (int h = 0; h < 2; ++h) {
        const int k0 = h * 64;
        for (int i = t * 4; i < 128 * 64; i += 512 * 4) {
            int r = i >> 6, kk = i & 63;
            float4 v = {0.f, 0.f, 0.f, 0.f};
            if (row0 + r < n) v = *(const float4*)(X + (size_t)(row0 + r) * 128 + k0 + kk);
            *(float4*)(Xl + r * 64 + (kk ^ (((r >> 3) & 7) << 2))) = v;
        }
        for (int i = t * 4; i < 64 * DOUT; i += 512 * 4) {
            int kk = i / DOUT, c0 = i % DOUT;
            float4 w4 = *(const float4*)(W + (size_t)(k0 + kk) * DOUT + c0);
            float wvv[4] = {w4.x, w4.y, w4.z, w4.w};
#pragma unroll
            for (int j = 0; j < 4; ++j) {
                int c = c0 + j;
                Wt[c * 64 + (kk ^ (((c >> 3) & 7) << 2))] = wvv[j];
            }
        }
        __syncthreads();

        for (int k4 = 0; k4 < 64; k4 += 4) {
            float4 xv[8], wv[TN];
#pragma unroll
            for (int i = 0; i < 8; ++i)
                xv[i] = *(const float4*)(Xl + (tm * 8 + i) * 64 + (k4 ^ xs));
#pragma unroll
            for (int j = 0; j < TN; ++j)
                wv[j] = *(const float4*)(Wt + (tn * TN + j) * 64 + (k4 ^ ws));
#pragma unroll
            for (int i = 0; i < 8; ++i)
#pragma unroll
                for (int j = 0; j < TN; ++j)
                    acc[i][j] += xv[i].x * wv[j].x + xv[i].y * wv[j].y +
                                 xv[i].z * wv[j].z + xv[i].w * wv[j].w;
        }
        __syncthreads();
    }

#pragma unroll
    for (int i = 0; i < 8; ++i) {
        int r = row0 + tm * 8 + i;
        if (r < n) {
            if (TN == 4) {
                uint2 o = {pack2(acc[i][0], acc[i][1]), pack2(acc[i][2], acc[i][3])};
                *(uint2*)(Y + (size_t)r * 64 + tn * 2) = o;
            } else {
                Y[(size_t)r * 32 + tn] = pack2(acc[i][0], acc[i][1]);
            }
        }
    }
}

// One wave per node, D=128: lane covers dims 2*lane, 2*lane+1 (one bf16x2 uint
// per edge-row). h output f32.
__global__ __launch_bounds__(256) void prop128_kernel(const uint32* __restrict__ xwb,
                                                      const float* __restrict__ dis,
                                                      const int* __restrict__ ptr,
                                                      const int2* __restrict__ rec,
                                                      const float* __restrict__ bias,
                                                      float* __restrict__ out, int n) {
    const int wid = threadIdx.x >> 6;
    const int lane = threadIdx.x & 63;
    const int v = blockIdx.x * 4 + wid;
    if (v >= n) return;

    const float dv = dis[v];
    const int beg = ptr[v];
    const int end = ptr[v + 1];

    float acc0 = 0.f, acc1 = 0.f;
    for (int base = beg; base < end; base += 64) {
        const int m = end - base;
        int r_l = 0;
        float w_l = 0.f;
        if (lane < m) {
            int2 q = rec[base + lane];
            r_l = q.x;
            w_l = __int_as_float(q.y) * dis[r_l];
        }
        const int lim = m < 64 ? m : 64;
#pragma unroll 4
        for (int j = 0; j < lim; ++j) {
            int r = __shfl(r_l, j);
            float w = __shfl(w_l, j);
            uint32 g = xwb[(size_t)r * 64 + lane];
            acc0 += w * bflo(g);
            acc1 += w * bfhi(g);
        }
    }

    uint32 g = xwb[(size_t)v * 64 + lane];
    float r0 = dv * acc0 + dv * dv * bflo(g) + bias[lane * 2];
    float r1 = dv * acc1 + dv * dv * bfhi(g) + bias[lane * 2 + 1];
    r0 = fmaxf(r0, 0.f);
    r1 = fmaxf(r1, 0.f);
    float2 o = {r0, r1};
    *(float2*)(out + (size_t)v * 128 + lane * 2) = o;
}

// One wave per node, D=64: two edges per iteration (lane halves), each half
// covers dims 2*(lane&31), +1. Cross-half combine via shfl_xor(32) at the end.
__global__ __launch_bounds__(256) void prop64_kernel(const uint32* __restrict__ xwb,
                                                     const float* __restrict__ dis,
                                                     const int* __restrict__ ptr,
                                                     const int2* __restrict__ rec,
                                                     const float* __restrict__ bias,
                                                     float* __restrict__ out, int n) {
    const int wid = threadIdx.x >> 6;
    const int lane = threadIdx.x & 63;
    const int half = lane >> 5;
    const int dlane = lane & 31;
    const int v = blockIdx.x * 4 + wid;
    if (v >= n) return;

    const float dv = dis[v];
    const int beg = ptr[v];
    const int end = ptr[v + 1];

    float acc0 = 0.f, acc1 = 0.f;
    for (int base = beg; base < end; base += 64) {
        const int m = end - base;
        int r_l = 0;
        float w_l = 0.f;
        if (lane < m) {
            int2 q = rec[base + lane];
            r_l = q.x;
            w_l = __int_as_float(q.y) * dis[r_l];
        }
        const int lim = m < 64 ? m : 64;
#pragma unroll 2
        for (int j = 0; j < lim; j += 2) {
            int r0 = __shfl(r_l, j);
            float w0 = __shfl(w_l, j);
            int r1 = __shfl(r_l, j | 1);
            float w1 = __shfl(w_l, j | 1);   // w=0 past segment end
            int r = half ? r1 : r0;
            float w = half ? w1 : w0;
            uint32 g = xwb[(size_t)r * 32 + dlane];
            acc0 += w * bflo(g);
            acc1 += w * bfhi(g);
        }
    }
    acc0 += __shfl_xor(acc0, 32);
    acc1 += __shfl_xor(acc1, 32);

    if (lane < 32) {
        uint32 g = xwb[(size_t)v * 32 + lane];
        float r0 = dv * acc0 + dv * dv * bflo(g) + bias[lane * 2];
        float r1 = dv * acc1 + dv * dv * bfhi(g) + bias[lane * 2 + 1];
        float2 o = {r0, r1};
        *(float2*)(out + (size_t)v * 64 + lane * 2) = o;
    }
}

extern "C" void kernel_launch(void* const* d_in, const int* in_sizes, int n_in,
                              void* d_out, int out_size, void* d_ws, size_t ws_size,
                              hipStream_t stream) {
    const float* x  = (const float*)d_in[0];
    const void*  ei = d_in[1];
    const float* ew = (const float*)d_in[2];
    const float* W1 = (const float*)d_in[3];
    const float* b1 = (const float*)d_in[4];
    const float* W2 = (const float*)d_in[5];
    const float* b2 = (const float*)d_in[6];
    float* out = (float*)d_out;

    const int n = in_sizes[0] / 128;
    const int E = in_sizes[2];

    char* p = (char*)d_ws;
    size_t o = 0;
    auto alloc = [&](size_t bytes) -> void* {
        void* q = p + o;
        o += (bytes + 255) & ~(size_t)255;
        return q;
    };
    int*    flag   = (int*)alloc(4);
    int*    cnt    = (int*)alloc((size_t)n * 4);
    int*    ptr    = (int*)alloc(((size_t)n + 1) * 4);
    int*    bsum   = (int*)alloc(1024 * 4);
    float*  dis    = (float*)alloc((size_t)n * 4);
    int*    tick   = (int*)alloc((size_t)E * 4);
    int2*   rec    = (int2*)alloc((size_t)E * 8);
    uint32* bufA   = (uint32*)alloc((size_t)n * 64 * 4);  // xw1 bf16x2; later xw2
    float*  bufB   = (float*)alloc((size_t)n * 128 * 4);  // h (f32)

    const int nb = (n + 4095) / 4096;

    hipMemsetAsync(cnt, 0, (size_t)n * 4, stream);
    detect_kernel<<<1, 64, 0, stream>>>((const int*)ei, flag);
    count_kernel<<<2048, 256, 0, stream>>>(ei, cnt, tick, E, flag);
    scanA_kernel<<<nb, 1024, 0, stream>>>(cnt, bsum, n);
    scanB_kernel<<<1, 1024, 0, stream>>>(bsum, nb);
    scanC_kernel<<<nb, 1024, 0, stream>>>(cnt, bsum, ptr, n, nb);
    scatter_kernel<<<2048, 256, 0, stream>>>(ei, ew, ptr, tick, rec, E, flag);
    degdis_kernel<<<(n + 255) / 256, 256, 0, stream>>>(ptr, rec, dis, n);

    gemm_kernel<128><<<(n + 127) / 128, 512, 0, stream>>>(x, W1, bufA, n);
    prop128_kernel<<<(n + 3) / 4, 256, 0, stream>>>(bufA, dis, ptr, rec, b1, bufB, n);
    gemm_kernel<64><<<(n + 127) / 128, 512, 0, stream>>>(bufB, W2, bufA, n);
    prop64_kernel<<<(n + 3) / 4, 256, 0, stream>>>(bufA, dis, ptr, rec, b2, out, n);
}

// Round 6
// 382.642 us; speedup vs baseline: 2.2138x; 1.0982x over previous
//
#include <hip/hip_runtime.h>
#include <stdint.h>

typedef unsigned int uint32;

// ---------------------------------------------------------------------------
// GCN 2-layer: out = GCNConv(relu(GCNConv(x, W1,b1)), W2,b2)
// deg[c] = sum ew into c, dis = rsqrt(deg+1)
// agg[c] = dis[c] * sum_e( w_e * xw[row_e] ) + dis[c]^2 * xw[c],
//   with w_e = dis[row_e]*ew_e PRE-FOLDED into ws_s by fold_kernel.
// xw staged as packed bf16x2 (halves gather traffic). Props read edge
// metadata via wave-uniform scalar loads (readfirstlane) -> s_load, no shfl.
// ---------------------------------------------------------------------------

__global__ void detect_kernel(const int* __restrict__ ei, int* flag) {
    if (threadIdx.x == 0 && blockIdx.x == 0) {
        int z = 0;
        for (int i = 0; i < 16; ++i) z |= ei[2 * i + 1];
        *flag = (z == 0) ? 1 : 0;
    }
}

// Counting pass; returned old value = edge's rank in its segment (ticket).
__global__ void count_kernel(const void* __restrict__ ei,
                             int* __restrict__ cnt, int* __restrict__ tick,
                             int E, const int* __restrict__ flag) {
    const int is64 = *flag;
    const int* e32 = (const int*)ei;
    const long long* e64 = (const long long*)ei;
    for (int e = blockIdx.x * blockDim.x + threadIdx.x; e < E;
         e += gridDim.x * blockDim.x) {
        int c = is64 ? (int)e64[(size_t)E + e] : e32[(size_t)E + e];
        tick[e] = atomicAdd(&cnt[c], 1);
    }
}

// ---------------------------------------------------------------------------
// 3-phase multi-block exclusive scan over cnt[0..n) -> ptr[0..n].
// ---------------------------------------------------------------------------
__global__ __launch_bounds__(1024) void scanA_kernel(const int* __restrict__ cnt,
                                                     int* __restrict__ bsum, int n) {
    __shared__ int sm[1024];
    const int t = threadIdx.x;
    const int base = blockIdx.x * 4096 + t * 4;
    int s = 0;
    if (base + 3 < n) {
        int4 v = *(const int4*)(cnt + base);
        s = v.x + v.y + v.z + v.w;
    } else {
        for (int i = 0; i < 4; ++i) if (base + i < n) s += cnt[base + i];
    }
    sm[t] = s;
    __syncthreads();
    for (int off = 512; off > 0; off >>= 1) {
        if (t < off) sm[t] += sm[t + off];
        __syncthreads();
    }
    if (t == 0) bsum[blockIdx.x] = sm[0];
}

__global__ __launch_bounds__(1024) void scanB_kernel(int* __restrict__ bsum, int nb) {
    __shared__ int sm[1024];
    const int t = threadIdx.x;
    sm[t] = (t < nb) ? bsum[t] : 0;
    __syncthreads();
    for (int off = 1; off < 1024; off <<= 1) {
        int v = (t >= off) ? sm[t - off] : 0;
        __syncthreads();
        sm[t] += v;
        __syncthreads();
    }
    if (t < nb) bsum[t] = (t == 0) ? 0 : sm[t - 1];  // exclusive
}

__global__ __launch_bounds__(1024) void scanC_kernel(const int* __restrict__ cnt,
                                                     const int* __restrict__ bsum,
                                                     int* __restrict__ ptr, int n, int nb) {
    __shared__ int sm[1024];
    const int t = threadIdx.x;
    const int base = blockIdx.x * 4096 + t * 4;
    int v0 = 0, v1 = 0, v2 = 0, v3 = 0;
    if (base + 3 < n) {
        int4 v = *(const int4*)(cnt + base);
        v0 = v.x; v1 = v.y; v2 = v.z; v3 = v.w;
    } else {
        if (base + 0 < n) v0 = cnt[base + 0];
        if (base + 1 < n) v1 = cnt[base + 1];
        if (base + 2 < n) v2 = cnt[base + 2];
        if (base + 3 < n) v3 = cnt[base + 3];
    }
    int s = v0 + v1 + v2 + v3;
    sm[t] = s;
    __syncthreads();
    for (int off = 1; off < 1024; off <<= 1) {
        int v = (t >= off) ? sm[t - off] : 0;
        __syncthreads();
        sm[t] += v;
        __syncthreads();
    }
    int run = bsum[blockIdx.x] + ((t == 0) ? 0 : sm[t - 1]);
    if (base + 0 < n) ptr[base + 0] = run;
    run += v0;
    if (base + 1 < n) ptr[base + 1] = run;
    run += v1;
    if (base + 2 < n) ptr[base + 2] = run;
    run += v2;
    if (base + 3 < n) ptr[base + 3] = run;
    run += v3;
    if (base <= n && base + 4 > n) ptr[n] = run;
}

// Atomic-free scatter: pos = ptr[c] + tick[e]. Split arrays {row}, {raw ew}.
__global__ void scatter_kernel(const void* __restrict__ ei, const float* __restrict__ ew,
                               const int* __restrict__ ptr, const int* __restrict__ tick,
                               int* __restrict__ rows_s, float* __restrict__ ws_s,
                               int E, const int* __restrict__ flag) {
    const int is64 = *flag;
    const int* e32 = (const int*)ei;
    const long long* e64 = (const long long*)ei;
    for (int e = blockIdx.x * blockDim.x + threadIdx.x; e < E;
         e += gridDim.x * blockDim.x) {
        int r, c;
        if (is64) { r = (int)e64[e]; c = (int)e64[(size_t)E + e]; }
        else      { r = e32[e];      c = e32[(size_t)E + e]; }
        int pos = ptr[c] + tick[e];
        rows_s[pos] = r;
        ws_s[pos] = ew[e];
    }
}

// deg[v] = sum of raw ws over v's CSR segment; dis = rsqrt(deg+1).
__global__ void degdis_kernel(const int* __restrict__ ptr, const float* __restrict__ ws_s,
                              float* __restrict__ dis, int n) {
    int v = blockIdx.x * blockDim.x + threadIdx.x;
    if (v >= n) return;
    float s = 0.f;
    const int e1 = ptr[v + 1];
    for (int e = ptr[v]; e < e1; ++e) s += ws_s[e];
    dis[v] = rsqrtf(s + 1.0f);
}

// Pre-fold dis[row] into the edge weight: ws_s[e] *= dis[rows_s[e]].
__global__ void fold_kernel(const int* __restrict__ rows_s, float* __restrict__ ws_s,
                            const float* __restrict__ dis, int E) {
    for (int e = blockIdx.x * blockDim.x + threadIdx.x; e < E;
         e += gridDim.x * blockDim.x)
        ws_s[e] *= dis[rows_s[e]];
}

__device__ inline uint32 bf16rne(float f) {
    uint32 u = __float_as_uint(f);
    u += 0x7FFF + ((u >> 16) & 1);
    return u >> 16;
}
__device__ inline uint32 pack2(float a, float b) { return bf16rne(a) | (bf16rne(b) << 16); }
__device__ inline float bflo(uint32 g) { return __uint_as_float(g << 16); }
__device__ inline float bfhi(uint32 g) { return __uint_as_float(g & 0xFFFF0000u); }

// ---------------------------------------------------------------------------
// Y[n,DOUT] = X[n,128] @ W[128,DOUT], fp32 vector-ALU GEMM, bf16x2-packed out.
// ---------------------------------------------------------------------------
template <int DOUT>
__global__ __launch_bounds__(512, 4) void gemm_kernel(const float* __restrict__ X,
                                                      const float* __restrict__ W,
                                                      uint32* __restrict__ Y, int n) {
    constexpr int TN = DOUT / 32;  // 4 for DOUT=128, 2 for DOUT=64
    __shared__ float Xl[128 * 64];
    __shared__ float Wt[DOUT * 64];
    const int t = threadIdx.x;
    const int row0 = blockIdx.x * 128;
    const int tm = t & 15;
    const int tn = t >> 4;
    const int xs = (tm & 7) << 2;
    const int ws = (((tn * TN) >> 3) & 7) << 2;

    float acc[8][TN];
#pragma unroll
    for (int i = 0; i < 8; ++i)
#pragma unroll
        for (int j = 0; j < TN; ++j) acc[i][j] = 0.f;

    for (int h = 0; h < 2; ++h) {
        const int k0 = h * 64;
        for (int i = t * 4; i < 128 * 64; i += 512 * 4) {
            int r = i >> 6, kk = i & 63;
            float4 v = {0.f, 0.f, 0.f, 0.f};
            if (row0 + r < n) v = *(const float4*)(X + (size_t)(row0 + r) * 128 + k0 + kk);
            *(float4*)(Xl + r * 64 + (kk ^ (((r >> 3) & 7) << 2))) = v;
        }
        for (int i = t * 4; i < 64 * DOUT; i += 512 * 4) {
            int kk = i / DOUT, c0 = i % DOUT;
            float4 w4 = *(const float4*)(W + (size_t)(k0 + kk) * DOUT + c0);
            float wvv[4] = {w4.x, w4.y, w4.z, w4.w};
#pragma unroll
            for (int j = 0; j < 4; ++j) {
                int c = c0 + j;
                Wt[c * 64 + (kk ^ (((c >> 3) & 7) << 2))] = wvv[j];
            }
        }
        __syncthreads();

        for (int k4 = 0; k4 < 64; k4 += 4) {
            float4 xv[8], wv[TN];
#pragma unroll
            for (int i = 0; i < 8; ++i)
                xv[i] = *(const float4*)(Xl + (tm * 8 + i) * 64 + (k4 ^ xs));
#pragma unroll
            for (int j = 0; j < TN; ++j)
                wv[j] = *(const float4*)(Wt + (tn * TN + j) * 64 + (k4 ^ ws));
#pragma unroll
            for (int i = 0; i < 8; ++i)
#pragma unroll
                for (int j = 0; j < TN; ++j)
                    acc[i][j] += xv[i].x * wv[j].x + xv[i].y * wv[j].y +
                                 xv[i].z * wv[j].z + xv[i].w * wv[j].w;
        }
        __syncthreads();
    }

#pragma unroll
    for (int i = 0; i < 8; ++i) {
        int r = row0 + tm * 8 + i;
        if (r < n) {
            if (TN == 4) {
                uint2 o = {pack2(acc[i][0], acc[i][1]), pack2(acc[i][2], acc[i][3])};
                *(uint2*)(Y + (size_t)r * 64 + tn * 2) = o;
            } else {
                Y[(size_t)r * 32 + tn] = pack2(acc[i][0], acc[i][1]);
            }
        }
    }
}

// One wave per node, D=128: lane covers dims 2*lane..2*lane+1. Edge metadata
// read via wave-uniform scalar loads (beg/end readfirstlane'd); no shfl.
__global__ __launch_bounds__(256) void prop128_kernel(const uint32* __restrict__ xwb,
                                                      const float* __restrict__ dis,
                                                      const int* __restrict__ ptr,
                                                      const int* __restrict__ rows_s,
                                                      const float* __restrict__ ws_s,
                                                      const float* __restrict__ bias,
                                                      float* __restrict__ out, int n) {
    const int wid = threadIdx.x >> 6;
    const int lane = threadIdx.x & 63;
    const int v = blockIdx.x * 4 + wid;
    if (v >= n) return;

    const int beg = __builtin_amdgcn_readfirstlane(ptr[v]);
    const int end = __builtin_amdgcn_readfirstlane(ptr[v + 1]);
    const float dv = dis[v];

    float acc0 = 0.f, acc1 = 0.f;
    int e = beg;
    int head = (beg + 3) & ~3;
    if (head > end) head = end;
    for (; e < head; ++e) {
        int r = rows_s[e];
        float w = ws_s[e];
        uint32 g = xwb[(size_t)r * 64 + lane];
        acc0 += w * bflo(g);
        acc1 += w * bfhi(g);
    }
#pragma unroll 2
    for (; e + 4 <= end; e += 4) {
        int4 r4 = *(const int4*)(rows_s + e);
        float4 w4 = *(const float4*)(ws_s + e);
        uint32 g0 = xwb[(size_t)r4.x * 64 + lane];
        uint32 g1 = xwb[(size_t)r4.y * 64 + lane];
        uint32 g2 = xwb[(size_t)r4.z * 64 + lane];
        uint32 g3 = xwb[(size_t)r4.w * 64 + lane];
        acc0 += w4.x * bflo(g0); acc1 += w4.x * bfhi(g0);
        acc0 += w4.y * bflo(g1); acc1 += w4.y * bfhi(g1);
        acc0 += w4.z * bflo(g2); acc1 += w4.z * bfhi(g2);
        acc0 += w4.w * bflo(g3); acc1 += w4.w * bfhi(g3);
    }
    for (; e < end; ++e) {
        int r = rows_s[e];
        float w = ws_s[e];
        uint32 g = xwb[(size_t)r * 64 + lane];
        acc0 += w * bflo(g);
        acc1 += w * bfhi(g);
    }

    uint32 g = xwb[(size_t)v * 64 + lane];
    float r0 = dv * acc0 + dv * dv * bflo(g) + bias[lane * 2];
    float r1 = dv * acc1 + dv * dv * bfhi(g) + bias[lane * 2 + 1];
    r0 = fmaxf(r0, 0.f);
    r1 = fmaxf(r1, 0.f);
    float2 o = {r0, r1};
    *(float2*)(out + (size_t)v * 128 + lane * 2) = o;
}

// One wave per node, D=64: lane halves process 2 edges/iter; dims via
// dlane=lane&31 (bf16x2 each). shfl_xor(32) combine at the end.
__global__ __launch_bounds__(256) void prop64_kernel(const uint32* __restrict__ xwb,
                                                     const float* __restrict__ dis,
                                                     const int* __restrict__ ptr,
                                                     const int* __restrict__ rows_s,
                                                     const float* __restrict__ ws_s,
                                                     const float* __restrict__ bias,
                                                     float* __restrict__ out, int n) {
    const int wid = threadIdx.x >> 6;
    const int lane = threadIdx.x & 63;
    const int half = lane >> 5;
    const int dlane = lane & 31;
    const int v = blockIdx.x * 4 + wid;
    if (v >= n) return;

    const int beg = __builtin_amdgcn_readfirstlane(ptr[v]);
    const int end = __builtin_amdgcn_readfirstlane(ptr[v + 1]);
    const float dv = dis[v];

    float acc0 = 0.f, acc1 = 0.f;
    int e = beg;
    int head = (beg + 3) & ~3;
    if (head > end) head = end;
    for (; e < head; ++e) {  // single edge: half1 contributes 0
        int r = rows_s[e];
        float w = half ? 0.f : ws_s[e];
        uint32 g = xwb[(size_t)r * 32 + dlane];
        acc0 += w * bflo(g);
        acc1 += w * bfhi(g);
    }
#pragma unroll 2
    for (; e + 4 <= end; e += 4) {
        int4 r4 = *(const int4*)(rows_s + e);
        float4 w4 = *(const float4*)(ws_s + e);
        int rA = half ? r4.y : r4.x;
        float wA = half ? w4.y : w4.x;
        int rB = half ? r4.w : r4.z;
        float wB = half ? w4.w : w4.z;
        uint32 gA = xwb[(size_t)rA * 32 + dlane];
        uint32 gB = xwb[(size_t)rB * 32 + dlane];
        acc0 += wA * bflo(gA); acc1 += wA * bfhi(gA);
        acc0 += wB * bflo(gB); acc1 += wB * bfhi(gB);
    }
    if (e + 2 <= end) {  // aligned pair
        int2 r2 = *(const int2*)(rows_s + e);
        float2 w2 = *(const float2*)(ws_s + e);
        int r = half ? r2.y : r2.x;
        float w = half ? w2.y : w2.x;
        uint32 g = xwb[(size_t)r * 32 + dlane];
        acc0 += w * bflo(g);
        acc1 += w * bfhi(g);
        e += 2;
    }
    if (e < end) {
        int r = rows_s[e];
        float w = half ? 0.f : ws_s[e];
        uint32 g = xwb[(size_t)r * 32 + dlane];
        acc0 += w * bflo(g);
        acc1 += w * bfhi(g);
    }
    acc0 += __shfl_xor(acc0, 32);
    acc1 += __shfl_xor(acc1, 32);

    if (lane < 32) {
        uint32 g = xwb[(size_t)v * 32 + lane];
        float r0 = dv * acc0 + dv * dv * bflo(g) + bias[lane * 2];
        float r1 = dv * acc1 + dv * dv * bfhi(g) + bias[lane * 2 + 1];
        float2 o = {r0, r1};
        *(float2*)(out + (size_t)v * 64 + lane * 2) = o;
    }
}

extern "C" void kernel_launch(void* const* d_in, const int* in_sizes, int n_in,
                              void* d_out, int out_size, void* d_ws, size_t ws_size,
                              hipStream_t stream) {
    const float* x  = (const float*)d_in[0];
    const void*  ei = d_in[1];
    const float* ew = (const float*)d_in[2];
    const float* W1 = (const float*)d_in[3];
    const float* b1 = (const float*)d_in[4];
    const float* W2 = (const float*)d_in[5];
    const float* b2 = (const float*)d_in[6];
    float* out = (float*)d_out;

    const int n = in_sizes[0] / 128;
    const int E = in_sizes[2];

    char* p = (char*)d_ws;
    size_t o = 0;
    auto alloc = [&](size_t bytes) -> void* {
        void* q = p + o;
        o += (bytes + 255) & ~(size_t)255;
        return q;
    };
    int*    flag   = (int*)alloc(4);
    int*    cnt    = (int*)alloc((size_t)n * 4);
    int*    ptr    = (int*)alloc(((size_t)n + 1) * 4);
    int*    bsum   = (int*)alloc(1024 * 4);
    float*  dis    = (float*)alloc((size_t)n * 4);
    int*    tick   = (int*)alloc((size_t)E * 4);
    int*    rows_s = (int*)alloc(((size_t)E + 8) * 4);
    float*  ws_s   = (float*)alloc(((size_t)E + 8) * 4);
    uint32* bufA   = (uint32*)alloc((size_t)n * 64 * 4);  // xw1 bf16x2; later xw2
    float*  bufB   = (float*)alloc((size_t)n * 128 * 4);  // h (f32)

    const int nb = (n + 4095) / 4096;

    hipMemsetAsync(cnt, 0, (size_t)n * 4, stream);
    detect_kernel<<<1, 64, 0, stream>>>((const int*)ei, flag);
    count_kernel<<<2048, 256, 0, stream>>>(ei, cnt, tick, E, flag);
    scanA_kernel<<<nb, 1024, 0, stream>>>(cnt, bsum, n);
    scanB_kernel<<<1, 1024, 0, stream>>>(bsum, nb);
    scanC_kernel<<<nb, 1024, 0, stream>>>(cnt, bsum, ptr, n, nb);
    scatter_kernel<<<2048, 256, 0, stream>>>(ei, ew, ptr, tick, rows_s, ws_s, E, flag);
    degdis_kernel<<<(n + 255) / 256, 256, 0, stream>>>(ptr, ws_s, dis, n);
    fold_kernel<<<2048, 256, 0, stream>>>(rows_s, ws_s, dis, E);

    gemm_kernel<128><<<(n + 127) / 128, 512, 0, stream>>>(x, W1, bufA, n);
    prop128_kernel<<<(n + 3) / 4, 256, 0, stream>>>(bufA, dis, ptr, rows_s, ws_s, b1, bufB, n);
    gemm_kernel<64><<<(n + 127) / 128, 512, 0, stream>>>(bufB, W2, bufA, n);
    prop64_kernel<<<(n + 3) / 4, 256, 0, stream>>>(bufA, dis, ptr, rows_s, ws_s, b2, out, n);
}

// Round 7
// 317.339 us; speedup vs baseline: 2.6693x; 1.2058x over previous
//
#include <hip/hip_runtime.h>
#include <stdint.h>

typedef unsigned int uint32;
typedef _Float16 f16x8 __attribute__((ext_vector_type(8)));
typedef float f32x4 __attribute__((ext_vector_type(4)));

// ---------------------------------------------------------------------------
// GCN 2-layer: out = GCNConv(relu(GCNConv(x, W1,b1)), W2,b2)
// deg[c] = sum ew into c, dis = rsqrt(deg+1)
// agg[c] = dis[c] * sum_e( w_e * xw[row_e] ) + dis[c]^2 * xw[c],
//   w_e = dis[row_e]*ew_e pre-folded into ws_s.
// GEMMs via v_mfma_f32_16x16x32_f16 (f32 accum); xw / h tables stored as
// packed fp16x2 (4B per 2 dims) for the gather phase.
// ---------------------------------------------------------------------------

__global__ void detect_kernel(const int* __restrict__ ei, int* flag) {
    if (threadIdx.x == 0 && blockIdx.x == 0) {
        int z = 0;
        for (int i = 0; i < 16; ++i) z |= ei[2 * i + 1];
        *flag = (z == 0) ? 1 : 0;
    }
}

// Counting pass; returned old value = edge's rank in its segment (ticket).
__global__ void count_kernel(const void* __restrict__ ei,
                             int* __restrict__ cnt, int* __restrict__ tick,
                             int E, const int* __restrict__ flag) {
    const int is64 = *flag;
    const int* e32 = (const int*)ei;
    const long long* e64 = (const long long*)ei;
    for (int e = blockIdx.x * blockDim.x + threadIdx.x; e < E;
         e += gridDim.x * blockDim.x) {
        int c = is64 ? (int)e64[(size_t)E + e] : e32[(size_t)E + e];
        tick[e] = atomicAdd(&cnt[c], 1);
    }
}

// ---------------------------------------------------------------------------
// 3-phase multi-block exclusive scan over cnt[0..n) -> ptr[0..n].
// ---------------------------------------------------------------------------
__global__ __launch_bounds__(1024) void scanA_kernel(const int* __restrict__ cnt,
                                                     int* __restrict__ bsum, int n) {
    __shared__ int sm[1024];
    const int t = threadIdx.x;
    const int base = blockIdx.x * 4096 + t * 4;
    int s = 0;
    if (base + 3 < n) {
        int4 v = *(const int4*)(cnt + base);
        s = v.x + v.y + v.z + v.w;
    } else {
        for (int i = 0; i < 4; ++i) if (base + i < n) s += cnt[base + i];
    }
    sm[t] = s;
    __syncthreads();
    for (int off = 512; off > 0; off >>= 1) {
        if (t < off) sm[t] += sm[t + off];
        __syncthreads();
    }
    if (t == 0) bsum[blockIdx.x] = sm[0];
}

__global__ __launch_bounds__(1024) void scanB_kernel(int* __restrict__ bsum, int nb) {
    __shared__ int sm[1024];
    const int t = threadIdx.x;
    sm[t] = (t < nb) ? bsum[t] : 0;
    __syncthreads();
    for (int off = 1; off < 1024; off <<= 1) {
        int v = (t >= off) ? sm[t - off] : 0;
        __syncthreads();
        sm[t] += v;
        __syncthreads();
    }
    if (t < nb) bsum[t] = (t == 0) ? 0 : sm[t - 1];  // exclusive
}

__global__ __launch_bounds__(1024) void scanC_kernel(const int* __restrict__ cnt,
                                                     const int* __restrict__ bsum,
                                                     int* __restrict__ ptr, int n, int nb) {
    __shared__ int sm[1024];
    const int t = threadIdx.x;
    const int base = blockIdx.x * 4096 + t * 4;
    int v0 = 0, v1 = 0, v2 = 0, v3 = 0;
    if (base + 3 < n) {
        int4 v = *(const int4*)(cnt + base);
        v0 = v.x; v1 = v.y; v2 = v.z; v3 = v.w;
    } else {
        if (base + 0 < n) v0 = cnt[base + 0];
        if (base + 1 < n) v1 = cnt[base + 1];
        if (base + 2 < n) v2 = cnt[base + 2];
        if (base + 3 < n) v3 = cnt[base + 3];
    }
    int s = v0 + v1 + v2 + v3;
    sm[t] = s;
    __syncthreads();
    for (int off = 1; off < 1024; off <<= 1) {
        int v = (t >= off) ? sm[t - off] : 0;
        __syncthreads();
        sm[t] += v;
        __syncthreads();
    }
    int run = bsum[blockIdx.x] + ((t == 0) ? 0 : sm[t - 1]);
    if (base + 0 < n) ptr[base + 0] = run;
    run += v0;
    if (base + 1 < n) ptr[base + 1] = run;
    run += v1;
    if (base + 2 < n) ptr[base + 2] = run;
    run += v2;
    if (base + 3 < n) ptr[base + 3] = run;
    run += v3;
    if (base <= n && base + 4 > n) ptr[n] = run;
}

// Atomic-free scatter: pos = ptr[c] + tick[e]. Split arrays {row}, {raw ew}.
__global__ void scatter_kernel(const void* __restrict__ ei, const float* __restrict__ ew,
                               const int* __restrict__ ptr, const int* __restrict__ tick,
                               int* __restrict__ rows_s, float* __restrict__ ws_s,
                               int E, const int* __restrict__ flag) {
    const int is64 = *flag;
    const int* e32 = (const int*)ei;
    const long long* e64 = (const long long*)ei;
    for (int e = blockIdx.x * blockDim.x + threadIdx.x; e < E;
         e += gridDim.x * blockDim.x) {
        int r, c;
        if (is64) { r = (int)e64[e]; c = (int)e64[(size_t)E + e]; }
        else      { r = e32[e];      c = e32[(size_t)E + e]; }
        int pos = ptr[c] + tick[e];
        rows_s[pos] = r;
        ws_s[pos] = ew[e];
    }
}

// deg[v] = sum of raw ws over v's CSR segment; dis = rsqrt(deg+1).
__global__ void degdis_kernel(const int* __restrict__ ptr, const float* __restrict__ ws_s,
                              float* __restrict__ dis, int n) {
    int v = blockIdx.x * blockDim.x + threadIdx.x;
    if (v >= n) return;
    float s = 0.f;
    const int e1 = ptr[v + 1];
    for (int e = ptr[v]; e < e1; ++e) s += ws_s[e];
    dis[v] = rsqrtf(s + 1.0f);
}

// Pre-fold dis[row] into the edge weight: ws_s[e] *= dis[rows_s[e]].
__global__ void fold_kernel(const int* __restrict__ rows_s, float* __restrict__ ws_s,
                            const float* __restrict__ dis, int E) {
    for (int e = blockIdx.x * blockDim.x + threadIdx.x; e < E;
         e += gridDim.x * blockDim.x)
        ws_s[e] *= dis[rows_s[e]];
}

__device__ inline uint32 pack2h(float a, float b) {
    unsigned short ua = __builtin_bit_cast(unsigned short, (_Float16)a);
    unsigned short ub = __builtin_bit_cast(unsigned short, (_Float16)b);
    return (uint32)ua | ((uint32)ub << 16);
}
__device__ inline float h2lo(uint32 g) {
    return (float)__builtin_bit_cast(_Float16, (unsigned short)(g & 0xFFFFu));
}
__device__ inline float h2hi(uint32 g) {
    return (float)__builtin_bit_cast(_Float16, (unsigned short)(g >> 16));
}

// Byte offset of element k (fp16) within a 256B fragment-ordered row:
// K=32 blocks; within a block, elements laid out so each lane's 8-elem MFMA
// fragment (quarter lq=l>>4) is 16B contiguous: pos = ks*32 + q*8 + h*4 + r
// for k = ks*32 + h*16 + q*4 + r. Same permutation for A and B => D invariant.
__device__ inline int kposb(int k) {
    return ((k >> 5) << 6) + (((k >> 2) & 3) << 4) + (((k >> 4) & 1) << 3) + ((k & 3) << 1);
}

// ---------------------------------------------------------------------------
// Y[n,DOUT] = X[n,128] @ W[128,DOUT] via mfma_f32_16x16x32_f16.
// 256 thr / 4 waves; 128-row tile, full K=128 staged fp16 in LDS (frag-ordered
// + XOR swizzle (row&7)<<4 => conflict-free 16B frag reads). Wave w: rows
// w*32..+32 (2 row-frags) x all DOUT cols. C/D: row=(l>>4)*4+reg, col=l&15.
// PACKED: X source is fp16x2-packed uints (layer 2); else f32 (layer 1).
// Y is fp16 (2B) scalars == packed fp16x2 table.
// ---------------------------------------------------------------------------
template <int DOUT, bool PACKED>
__global__ __launch_bounds__(256, 2) void mgemm_kernel(const void* __restrict__ Xv,
                                                       const float* __restrict__ W,
                                                       unsigned short* __restrict__ Y,
                                                       int n) {
    constexpr int NC = DOUT / 16;  // col-frags: 8 (DOUT=128) or 4 (DOUT=64)
    __shared__ __align__(16) unsigned short Xl[128 * 128];
    __shared__ __align__(16) unsigned short Wl[DOUT * 128];
    const int t = threadIdx.x;
    const int row0 = blockIdx.x * 128;

    // Stage X tile (fp16, frag-ordered, swizzled), zero-padded past n.
    for (int i = t * 4; i < 128 * 128; i += 1024) {
        int r = i >> 7, k = i & 127;
        uint2 st;
        if (PACKED) {
            uint2 v = {0u, 0u};
            if (row0 + r < n)
                v = *(const uint2*)((const uint32*)Xv + (size_t)(row0 + r) * 64 + (k >> 1));
            st = v;
        } else {
            float4 v = {0.f, 0.f, 0.f, 0.f};
            if (row0 + r < n)
                v = *(const float4*)((const float*)Xv + (size_t)(row0 + r) * 128 + k);
            st.x = pack2h(v.x, v.y);
            st.y = pack2h(v.z, v.w);
        }
        *(uint2*)((char*)Xl + r * 256 + (kposb(k) ^ ((r & 7) << 4))) = st;
    }
    // Stage W^T fp16: Wl[c][k] frag-ordered, swizzled by (c&7)<<4.
    for (int i = t; i < 128 * (DOUT / 4); i += 256) {
        int k = i / (DOUT / 4);
        int c0 = (i % (DOUT / 4)) * 4;
        float4 wv = *(const float4*)(W + (size_t)k * DOUT + c0);
        float a[4] = {wv.x, wv.y, wv.z, wv.w};
        int kb = kposb(k);
#pragma unroll
        for (int j = 0; j < 4; ++j) {
            int c = c0 + j;
            *(unsigned short*)((char*)Wl + c * 256 + (kb ^ ((c & 7) << 4))) =
                __builtin_bit_cast(unsigned short, (_Float16)a[j]);
        }
    }
    __syncthreads();

    const int l = t & 63;
    const int w = t >> 6;
    const int lr = l & 15;
    const int lq = l >> 4;
    const int rbase = w * 32;
    const int swz = (lr & 7) << 4;

    f32x4 acc[2][NC];
#pragma unroll
    for (int i = 0; i < 2; ++i)
#pragma unroll
        for (int c = 0; c < NC; ++c) acc[i][c] = (f32x4){0.f, 0.f, 0.f, 0.f};

#pragma unroll
    for (int ks = 0; ks < 4; ++ks) {
        const int fo = ks * 64 + lq * 16;
        f16x8 a0 = *(const f16x8*)((const char*)Xl + (rbase + lr) * 256 + (fo ^ swz));
        f16x8 a1 = *(const f16x8*)((const char*)Xl + (rbase + 16 + lr) * 256 + (fo ^ swz));
#pragma unroll
        for (int c = 0; c < NC; ++c) {
            f16x8 b = *(const f16x8*)((const char*)Wl + (c * 16 + lr) * 256 + (fo ^ swz));
            acc[0][c] = __builtin_amdgcn_mfma_f32_16x16x32_f16(a0, b, acc[0][c], 0, 0, 0);
            acc[1][c] = __builtin_amdgcn_mfma_f32_16x16x32_f16(a1, b, acc[1][c], 0, 0, 0);
        }
    }

#pragma unroll
    for (int i = 0; i < 2; ++i) {
#pragma unroll
        for (int c = 0; c < NC; ++c) {
#pragma unroll
            for (int reg = 0; reg < 4; ++reg) {
                int row = row0 + rbase + i * 16 + lq * 4 + reg;
                if (row < n)
                    Y[(size_t)row * DOUT + c * 16 + lr] =
                        __builtin_bit_cast(unsigned short, (_Float16)acc[i][c][reg]);
            }
        }
    }
}

// One wave per node, D=128: lane covers dims 2*lane..2*lane+1 (one fp16x2).
// Edge metadata via wave-uniform scalar loads; h output packed fp16x2.
__global__ __launch_bounds__(256) void prop128_kernel(const uint32* __restrict__ xwb,
                                                      const float* __restrict__ dis,
                                                      const int* __restrict__ ptr,
                                                      const int* __restrict__ rows_s,
                                                      const float* __restrict__ ws_s,
                                                      const float* __restrict__ bias,
                                                      uint32* __restrict__ out, int n) {
    const int wid = threadIdx.x >> 6;
    const int lane = threadIdx.x & 63;
    const int v = blockIdx.x * 4 + wid;
    if (v >= n) return;

    const int beg = __builtin_amdgcn_readfirstlane(ptr[v]);
    const int end = __builtin_amdgcn_readfirstlane(ptr[v + 1]);
    const float dv = dis[v];

    float acc0 = 0.f, acc1 = 0.f;
    int e = beg;
    int head = (beg + 3) & ~3;
    if (head > end) head = end;
    for (; e < head; ++e) {
        int r = rows_s[e];
        float w = ws_s[e];
        uint32 g = xwb[(size_t)r * 64 + lane];
        acc0 += w * h2lo(g);
        acc1 += w * h2hi(g);
    }
#pragma unroll 2
    for (; e + 4 <= end; e += 4) {
        int4 r4 = *(const int4*)(rows_s + e);
        float4 w4 = *(const float4*)(ws_s + e);
        uint32 g0 = xwb[(size_t)r4.x * 64 + lane];
        uint32 g1 = xwb[(size_t)r4.y * 64 + lane];
        uint32 g2 = xwb[(size_t)r4.z * 64 + lane];
        uint32 g3 = xwb[(size_t)r4.w * 64 + lane];
        acc0 += w4.x * h2lo(g0); acc1 += w4.x * h2hi(g0);
        acc0 += w4.y * h2lo(g1); acc1 += w4.y * h2hi(g1);
        acc0 += w4.z * h2lo(g2); acc1 += w4.z * h2hi(g2);
        acc0 += w4.w * h2lo(g3); acc1 += w4.w * h2hi(g3);
    }
    for (; e < end; ++e) {
        int r = rows_s[e];
        float w = ws_s[e];
        uint32 g = xwb[(size_t)r * 64 + lane];
        acc0 += w * h2lo(g);
        acc1 += w * h2hi(g);
    }

    uint32 g = xwb[(size_t)v * 64 + lane];
    float r0 = dv * acc0 + dv * dv * h2lo(g) + bias[lane * 2];
    float r1 = dv * acc1 + dv * dv * h2hi(g) + bias[lane * 2 + 1];
    r0 = fmaxf(r0, 0.f);
    r1 = fmaxf(r1, 0.f);
    out[(size_t)v * 64 + lane] = pack2h(r0, r1);
}

// One wave per node, D=64: lane halves process 2 edges/iter; dims via
// dlane=lane&31 (fp16x2 each). shfl_xor(32) combine; f32 final output.
__global__ __launch_bounds__(256) void prop64_kernel(const uint32* __restrict__ xwb,
                                                     const float* __restrict__ dis,
                                                     const int* __restrict__ ptr,
                                                     const int* __restrict__ rows_s,
                                                     const float* __restrict__ ws_s,
                                                     const float* __restrict__ bias,
                                                     float* __restrict__ out, int n) {
    const int wid = threadIdx.x >> 6;
    const int lane = threadIdx.x & 63;
    const int half = lane >> 5;
    const int dlane = lane & 31;
    const int v = blockIdx.x * 4 + wid;
    if (v >= n) return;

    const int beg = __builtin_amdgcn_readfirstlane(ptr[v]);
    const int end = __builtin_amdgcn_readfirstlane(ptr[v + 1]);
    const float dv = dis[v];

    float acc0 = 0.f, acc1 = 0.f;
    int e = beg;
    int head = (beg + 3) & ~3;
    if (head > end) head = end;
    for (; e < head; ++e) {
        int r = rows_s[e];
        float w = half ? 0.f : ws_s[e];
        uint32 g = xwb[(size_t)r * 32 + dlane];
        acc0 += w * h2lo(g);
        acc1 += w * h2hi(g);
    }
#pragma unroll 2
    for (; e + 4 <= end; e += 4) {
        int4 r4 = *(const int4*)(rows_s + e);
        float4 w4 = *(const float4*)(ws_s + e);
        int rA = half ? r4.y : r4.x;
        float wA = half ? w4.y : w4.x;
        int rB = half ? r4.w : r4.z;
        float wB = half ? w4.w : w4.z;
        uint32 gA = xwb[(size_t)rA * 32 + dlane];
        uint32 gB = xwb[(size_t)rB * 32 + dlane];
        acc0 += wA * h2lo(gA); acc1 += wA * h2hi(gA);
        acc0 += wB * h2lo(gB); acc1 += wB * h2hi(gB);
    }
    if (e + 2 <= end) {
        int2 r2 = *(const int2*)(rows_s + e);
        float2 w2 = *(const float2*)(ws_s + e);
        int r = half ? r2.y : r2.x;
        float w = half ? w2.y : w2.x;
        uint32 g = xwb[(size_t)r * 32 + dlane];
        acc0 += w * h2lo(g);
        acc1 += w * h2hi(g);
        e += 2;
    }
    if (e < end) {
        int r = rows_s[e];
        float w = half ? 0.f : ws_s[e];
        uint32 g = xwb[(size_t)r * 32 + dlane];
        acc0 += w * h2lo(g);
        acc1 += w * h2hi(g);
    }
    acc0 += __shfl_xor(acc0, 32);
    acc1 += __shfl_xor(acc1, 32);

    if (lane < 32) {
        uint32 g = xwb[(size_t)v * 32 + lane];
        float r0 = dv * acc0 + dv * dv * h2lo(g) + bias[lane * 2];
        float r1 = dv * acc1 + dv * dv * h2hi(g) + bias[lane * 2 + 1];
        float2 o = {r0, r1};
        *(float2*)(out + (size_t)v * 64 + lane * 2) = o;
    }
}

extern "C" void kernel_launch(void* const* d_in, const int* in_sizes, int n_in,
                              void* d_out, int out_size, void* d_ws, size_t ws_size,
                              hipStream_t stream) {
    const float* x  = (const float*)d_in[0];
    const void*  ei = d_in[1];
    const float* ew = (const float*)d_in[2];
    const float* W1 = (const float*)d_in[3];
    const float* b1 = (const float*)d_in[4];
    const float* W2 = (const float*)d_in[5];
    const float* b2 = (const float*)d_in[6];
    float* out = (float*)d_out;

    const int n = in_sizes[0] / 128;
    const int E = in_sizes[2];

    char* p = (char*)d_ws;
    size_t o = 0;
    auto alloc = [&](size_t bytes) -> void* {
        void* q = p + o;
        o += (bytes + 255) & ~(size_t)255;
        return q;
    };
    int*    flag   = (int*)alloc(4);
    int*    cnt    = (int*)alloc((size_t)n * 4);
    int*    ptr    = (int*)alloc(((size_t)n + 1) * 4);
    int*    bsum   = (int*)alloc(1024 * 4);
    float*  dis    = (float*)alloc((size_t)n * 4);
    int*    tick   = (int*)alloc((size_t)E * 4);
    int*    rows_s = (int*)alloc(((size_t)E + 8) * 4);
    float*  ws_s   = (float*)alloc(((size_t)E + 8) * 4);
    uint32* bufA   = (uint32*)alloc((size_t)n * 64 * 4);  // xw1/xw2 fp16x2 table
    uint32* bufB   = (uint32*)alloc((size_t)n * 64 * 4);  // h fp16x2 table

    const int nb = (n + 4095) / 4096;
    const int gblk = (n + 127) / 128;

    hipMemsetAsync(cnt, 0, (size_t)n * 4, stream);
    detect_kernel<<<1, 64, 0, stream>>>((const int*)ei, flag);
    count_kernel<<<2048, 256, 0, stream>>>(ei, cnt, tick, E, flag);
    scanA_kernel<<<nb, 1024, 0, stream>>>(cnt, bsum, n);
    scanB_kernel<<<1, 1024, 0, stream>>>(bsum, nb);
    scanC_kernel<<<nb, 1024, 0, stream>>>(cnt, bsum, ptr, n, nb);
    scatter_kernel<<<2048, 256, 0, stream>>>(ei, ew, ptr, tick, rows_s, ws_s, E, flag);
    degdis_kernel<<<(n + 255) / 256, 256, 0, stream>>>(ptr, ws_s, dis, n);
    fold_kernel<<<2048, 256, 0, stream>>>(rows_s, ws_s, dis, E);

    mgemm_kernel<128, false><<<gblk, 256, 0, stream>>>(x, W1, (unsigned short*)bufA, n);
    prop128_kernel<<<(n + 3) / 4, 256, 0, stream>>>(bufA, dis, ptr, rows_s, ws_s, b1, bufB, n);
    mgemm_kernel<64, true><<<gblk, 256, 0, stream>>>(bufB, W2, (unsigned short*)bufA, n);
    prop64_kernel<<<(n + 3) / 4, 256, 0, stream>>>(bufA, dis, ptr, rows_s, ws_s, b2, out, n);
}

// Round 8
// 256.573 us; speedup vs baseline: 3.3015x; 1.2368x over previous
//
#include <hip/hip_runtime.h>
#include <stdint.h>

typedef unsigned int uint32;
typedef _Float16 f16x8 __attribute__((ext_vector_type(8)));
typedef float f32x4 __attribute__((ext_vector_type(4)));

// ---------------------------------------------------------------------------
// GCN 2-layer: out = GCNConv(relu(GCNConv(x, W1,b1)), W2,b2)
// deg[c] = sum ew into c, dis = rsqrt(deg+1)
// agg[c] = dis[c] * sum_e( w_e * xw[row_e] ) + dis[c]^2 * xw[c],
//   w_e = dis[row_e]*ew_e pre-folded into ws_s.
// CSR built via atomic-free 2-level bucket sort (64-node buckets):
//   p1 per-block LDS histograms -> s1/s2 scans -> p2 bucketed append
//   (disjoint reserved ranges, L2-local writes) -> p3 per-bucket LDS CSR
//   (+ptr +deg/dis fused). GEMMs via mfma_f32_16x16x32_f16; xw/h tables
//   packed fp16x2 for the gather phase.
// ---------------------------------------------------------------------------

#define NPBSH 6
#define NPB 64
#define PBLK 256
#define CAP 2048

__global__ void detect_kernel(const int* __restrict__ ei, int* flag) {
    if (threadIdx.x == 0 && blockIdx.x == 0) {
        int z = 0;
        for (int i = 0; i < 16; ++i) z |= ei[2 * i + 1];
        *flag = (z == 0) ? 1 : 0;
    }
}

// p1: per-block bucket histogram (LDS), no global atomics.
__global__ __launch_bounds__(512) void p1_hist(const void* __restrict__ ei, int E, int NB,
                                               int chunk, const int* __restrict__ flag,
                                               int* __restrict__ cnt_bb) {
    extern __shared__ int h[];
    const int t = threadIdx.x, blk = blockIdx.x;
    for (int i = t; i < NB; i += 512) h[i] = 0;
    __syncthreads();
    const int is64 = *flag;
    const int* e32 = (const int*)ei;
    const long long* e64 = (const long long*)ei;
    const int e0 = blk * chunk;
    const int e1 = min(e0 + chunk, E);
    for (int e = e0 + t; e < e1; e += 512) {
        int c = is64 ? (int)e64[(size_t)E + e] : e32[(size_t)E + e];
        atomicAdd(&h[c >> NPBSH], 1);
    }
    __syncthreads();
    for (int i = t; i < NB; i += 512) cnt_bb[(size_t)blk * NB + i] = h[i];
}

// s1: per-bucket column scan over PBLK block-counts -> boff_rel + totals.
__global__ __launch_bounds__(PBLK) void s1_colscan(const int* __restrict__ cnt_bb,
                                                   int* __restrict__ boff_rel,
                                                   int* __restrict__ tb, int NB) {
    __shared__ int sm[PBLK];
    const int t = threadIdx.x, b = blockIdx.x;
    int v = cnt_bb[(size_t)t * NB + b];
    sm[t] = v;
    __syncthreads();
    for (int off = 1; off < PBLK; off <<= 1) {
        int u = (t >= off) ? sm[t - off] : 0;
        __syncthreads();
        sm[t] += u;
        __syncthreads();
    }
    boff_rel[(size_t)t * NB + b] = sm[t] - v;  // exclusive prefix over blocks
    if (t == PBLK - 1) tb[b] = sm[PBLK - 1];
}

// s2: single-block chunked exclusive scan (tb[0..n) -> ptr[0..n], ptr[n]=total).
__global__ __launch_bounds__(1024) void scan_kernel(const int* __restrict__ cnt,
                                                    int* __restrict__ ptr, int n) {
    __shared__ int sm[1024];
    const int t = threadIdx.x;
    const int chunk = (n + 1023) / 1024;
    const int start = t * chunk;
    const int end = min(start + chunk, n);
    int s = 0;
    for (int i = start; i < end; ++i) s += cnt[i];
    sm[t] = s;
    __syncthreads();
    for (int off = 1; off < 1024; off <<= 1) {
        int v = (t >= off) ? sm[t - off] : 0;
        __syncthreads();
        sm[t] += v;
        __syncthreads();
    }
    int run = (t == 0) ? 0 : sm[t - 1];
    for (int i = start; i < end; ++i) { ptr[i] = run; run += cnt[i]; }
    if (start < n && end == n) ptr[n] = run;
}

// p2: bucketed append. LDS cursors start at reserved disjoint ranges.
__global__ __launch_bounds__(512) void p2_scatter(const void* __restrict__ ei,
                                                  const float* __restrict__ ew,
                                                  int E, int NB, int chunk,
                                                  const int* __restrict__ flag,
                                                  const int* __restrict__ bstart,
                                                  const int* __restrict__ boff_rel,
                                                  int2* __restrict__ bktrec,
                                                  unsigned short* __restrict__ bktc) {
    extern __shared__ int cur[];
    const int t = threadIdx.x, blk = blockIdx.x;
    for (int i = t; i < NB; i += 512)
        cur[i] = bstart[i] + boff_rel[(size_t)blk * NB + i];
    __syncthreads();
    const int is64 = *flag;
    const int* e32 = (const int*)ei;
    const long long* e64 = (const long long*)ei;
    const int e0 = blk * chunk;
    const int e1 = min(e0 + chunk, E);
    for (int e = e0 + t; e < e1; e += 512) {
        int r, c;
        if (is64) { r = (int)e64[e]; c = (int)e64[(size_t)E + e]; }
        else      { r = e32[e];      c = e32[(size_t)E + e]; }
        int b = c >> NPBSH;
        int pos = atomicAdd(&cur[b], 1);
        bktrec[pos] = make_int2(r, __float_as_int(ew[e]));
        bktc[pos] = (unsigned short)(c & (NPB - 1));
    }
}

// p3: per-bucket CSR build in LDS + ptr + fused deg/dis.
__global__ __launch_bounds__(256) void p3_build(const int* __restrict__ bstart,
                                                const int2* __restrict__ bktrec,
                                                const unsigned short* __restrict__ bktc,
                                                int* __restrict__ ptr, int* __restrict__ rows_s,
                                                float* __restrict__ ws_s, float* __restrict__ dis,
                                                int n, int NB, int E) {
    __shared__ int inr[CAP];
    __shared__ float inw[CAP];
    __shared__ unsigned short inc[CAP];
    __shared__ int outr[CAP];
    __shared__ float outw[CAP];
    __shared__ int h[NPB], ex[NPB + 1], cu[NPB];
    const int t = threadIdx.x, b = blockIdx.x;
    const int base = bstart[b];
    const int eb = bstart[b + 1] - base;
    const int j0 = b << NPBSH;
    const int ncount = min(NPB, n - j0);
    if (t < NPB) { h[t] = 0; cu[t] = 0; }
    __syncthreads();

    if (eb <= CAP) {
        for (int i = t; i < eb; i += 256) {
            int2 rc = bktrec[base + i];
            inr[i] = rc.x;
            inw[i] = __int_as_float(rc.y);
            int cl = bktc[base + i];
            inc[i] = (unsigned short)cl;
            atomicAdd(&h[cl], 1);
        }
        __syncthreads();
        if (t == 0) {
            int run = 0;
            for (int j = 0; j < NPB; ++j) { ex[j] = run; run += h[j]; }
            ex[NPB] = run;
        }
        __syncthreads();
        for (int i = t; i < eb; i += 256) {
            int cl = inc[i];
            int d = ex[cl] + atomicAdd(&cu[cl], 1);
            outr[d] = inr[i];
            outw[d] = inw[i];
        }
        __syncthreads();
        for (int i = t; i < eb; i += 256) {
            rows_s[base + i] = outr[i];
            ws_s[base + i] = outw[i];
        }
        if (t < ncount) {
            ptr[j0 + t] = base + ex[t];
            float s = 0.f;
            for (int i = ex[t]; i < ex[t] + h[t]; ++i) s += outw[i];
            dis[j0 + t] = rsqrtf(s + 1.0f);
        }
    } else {  // fallback (eb > CAP): global two-pass, still correct
        for (int i = t; i < eb; i += 256) atomicAdd(&h[bktc[base + i]], 1);
        __syncthreads();
        if (t == 0) {
            int run = 0;
            for (int j = 0; j < NPB; ++j) { ex[j] = run; run += h[j]; }
            ex[NPB] = run;
        }
        __syncthreads();
        for (int i = t; i < eb; i += 256) {
            int2 rc = bktrec[base + i];
            int cl = bktc[base + i];
            int d = ex[cl] + atomicAdd(&cu[cl], 1);
            rows_s[base + d] = rc.x;
            ws_s[base + d] = __int_as_float(rc.y);
        }
        __syncthreads();
        if (t < ncount) {
            ptr[j0 + t] = base + ex[t];
            float s = 0.f;
            for (int i = base + ex[t]; i < base + ex[t] + h[t]; ++i) s += ws_s[i];
            dis[j0 + t] = rsqrtf(s + 1.0f);
        }
    }
    if (b == NB - 1 && t == 0) ptr[n] = E;
}

// Pre-fold dis[row] into the edge weight: ws_s[e] *= dis[rows_s[e]].
__global__ void fold_kernel(const int* __restrict__ rows_s, float* __restrict__ ws_s,
                            const float* __restrict__ dis, int E) {
    for (int e = blockIdx.x * blockDim.x + threadIdx.x; e < E;
         e += gridDim.x * blockDim.x)
        ws_s[e] *= dis[rows_s[e]];
}

__device__ inline uint32 pack2h(float a, float b) {
    unsigned short ua = __builtin_bit_cast(unsigned short, (_Float16)a);
    unsigned short ub = __builtin_bit_cast(unsigned short, (_Float16)b);
    return (uint32)ua | ((uint32)ub << 16);
}
__device__ inline float h2lo(uint32 g) {
    return (float)__builtin_bit_cast(_Float16, (unsigned short)(g & 0xFFFFu));
}
__device__ inline float h2hi(uint32 g) {
    return (float)__builtin_bit_cast(_Float16, (unsigned short)(g >> 16));
}

// Byte offset of fp16 element k within a 256B fragment-ordered row (same
// permutation applied to A and B keeps D = A*B invariant).
__device__ inline int kposb(int k) {
    return ((k >> 5) << 6) + (((k >> 2) & 3) << 4) + (((k >> 4) & 1) << 3) + ((k & 3) << 1);
}

// ---------------------------------------------------------------------------
// Y[n,DOUT] = X[n,128] @ W[128,DOUT] via mfma_f32_16x16x32_f16 (f32 accum).
// ---------------------------------------------------------------------------
template <int DOUT, bool PACKED>
__global__ __launch_bounds__(256, 2) void mgemm_kernel(const void* __restrict__ Xv,
                                                       const float* __restrict__ W,
                                                       unsigned short* __restrict__ Y,
                                                       int n) {
    constexpr int NC = DOUT / 16;
    __shared__ __align__(16) unsigned short Xl[128 * 128];
    __shared__ __align__(16) unsigned short Wl[DOUT * 128];
    const int t = threadIdx.x;
    const int row0 = blockIdx.x * 128;

    for (int i = t * 4; i < 128 * 128; i += 1024) {
        int r = i >> 7, k = i & 127;
        uint2 st;
        if (PACKED) {
            uint2 v = {0u, 0u};
            if (row0 + r < n)
                v = *(const uint2*)((const uint32*)Xv + (size_t)(row0 + r) * 64 + (k >> 1));
            st = v;
        } else {
            float4 v = {0.f, 0.f, 0.f, 0.f};
            if (row0 + r < n)
                v = *(const float4*)((const float*)Xv + (size_t)(row0 + r) * 128 + k);
            st.x = pack2h(v.x, v.y);
            st.y = pack2h(v.z, v.w);
        }
        *(uint2*)((char*)Xl + r * 256 + (kposb(k) ^ ((r & 7) << 4))) = st;
    }
    for (int i = t; i < 128 * (DOUT / 4); i += 256) {
        int k = i / (DOUT / 4);
        int c0 = (i % (DOUT / 4)) * 4;
        float4 wv = *(const float4*)(W + (size_t)k * DOUT + c0);
        float a[4] = {wv.x, wv.y, wv.z, wv.w};
        int kb = kposb(k);
#pragma unroll
        for (int j = 0; j < 4; ++j) {
            int c = c0 + j;
            *(unsigned short*)((char*)Wl + c * 256 + (kb ^ ((c & 7) << 4))) =
                __builtin_bit_cast(unsigned short, (_Float16)a[j]);
        }
    }
    __syncthreads();

    const int l = t & 63;
    const int w = t >> 6;
    const int lr = l & 15;
    const int lq = l >> 4;
    const int rbase = w * 32;
    const int swz = (lr & 7) << 4;

    f32x4 acc[2][NC];
#pragma unroll
    for (int i = 0; i < 2; ++i)
#pragma unroll
        for (int c = 0; c < NC; ++c) acc[i][c] = (f32x4){0.f, 0.f, 0.f, 0.f};

#pragma unroll
    for (int ks = 0; ks < 4; ++ks) {
        const int fo = ks * 64 + lq * 16;
        f16x8 a0 = *(const f16x8*)((const char*)Xl + (rbase + lr) * 256 + (fo ^ swz));
        f16x8 a1 = *(const f16x8*)((const char*)Xl + (rbase + 16 + lr) * 256 + (fo ^ swz));
#pragma unroll
        for (int c = 0; c < NC; ++c) {
            f16x8 b = *(const f16x8*)((const char*)Wl + (c * 16 + lr) * 256 + (fo ^ swz));
            acc[0][c] = __builtin_amdgcn_mfma_f32_16x16x32_f16(a0, b, acc[0][c], 0, 0, 0);
            acc[1][c] = __builtin_amdgcn_mfma_f32_16x16x32_f16(a1, b, acc[1][c], 0, 0, 0);
        }
    }

#pragma unroll
    for (int i = 0; i < 2; ++i) {
#pragma unroll
        for (int c = 0; c < NC; ++c) {
#pragma unroll
            for (int reg = 0; reg < 4; ++reg) {
                int row = row0 + rbase + i * 16 + lq * 4 + reg;
                if (row < n)
                    Y[(size_t)row * DOUT + c * 16 + lr] =
                        __builtin_bit_cast(unsigned short, (_Float16)acc[i][c][reg]);
            }
        }
    }
}

// One wave per node, D=128: lane covers dims 2*lane..2*lane+1 (one fp16x2).
__global__ __launch_bounds__(256) void prop128_kernel(const uint32* __restrict__ xwb,
                                                      const float* __restrict__ dis,
                                                      const int* __restrict__ ptr,
                                                      const int* __restrict__ rows_s,
                                                      const float* __restrict__ ws_s,
                                                      const float* __restrict__ bias,
                                                      uint32* __restrict__ out, int n) {
    const int wid = threadIdx.x >> 6;
    const int lane = threadIdx.x & 63;
    const int v = blockIdx.x * 4 + wid;
    if (v >= n) return;

    const int beg = __builtin_amdgcn_readfirstlane(ptr[v]);
    const int end = __builtin_amdgcn_readfirstlane(ptr[v + 1]);
    const float dv = dis[v];

    float acc0 = 0.f, acc1 = 0.f;
    int e = beg;
    int head = (beg + 3) & ~3;
    if (head > end) head = end;
    for (; e < head; ++e) {
        int r = rows_s[e];
        float w = ws_s[e];
        uint32 g = xwb[(size_t)r * 64 + lane];
        acc0 += w * h2lo(g);
        acc1 += w * h2hi(g);
    }
#pragma unroll 2
    for (; e + 4 <= end; e += 4) {
        int4 r4 = *(const int4*)(rows_s + e);
        float4 w4 = *(const float4*)(ws_s + e);
        uint32 g0 = xwb[(size_t)r4.x * 64 + lane];
        uint32 g1 = xwb[(size_t)r4.y * 64 + lane];
        uint32 g2 = xwb[(size_t)r4.z * 64 + lane];
        uint32 g3 = xwb[(size_t)r4.w * 64 + lane];
        acc0 += w4.x * h2lo(g0); acc1 += w4.x * h2hi(g0);
        acc0 += w4.y * h2lo(g1); acc1 += w4.y * h2hi(g1);
        acc0 += w4.z * h2lo(g2); acc1 += w4.z * h2hi(g2);
        acc0 += w4.w * h2lo(g3); acc1 += w4.w * h2hi(g3);
    }
    for (; e < end; ++e) {
        int r = rows_s[e];
        float w = ws_s[e];
        uint32 g = xwb[(size_t)r * 64 + lane];
        acc0 += w * h2lo(g);
        acc1 += w * h2hi(g);
    }

    uint32 g = xwb[(size_t)v * 64 + lane];
    float r0 = dv * acc0 + dv * dv * h2lo(g) + bias[lane * 2];
    float r1 = dv * acc1 + dv * dv * h2hi(g) + bias[lane * 2 + 1];
    r0 = fmaxf(r0, 0.f);
    r1 = fmaxf(r1, 0.f);
    out[(size_t)v * 64 + lane] = pack2h(r0, r1);
}

// One wave per node, D=64: lane halves process 2 edges/iter.
__global__ __launch_bounds__(256) void prop64_kernel(const uint32* __restrict__ xwb,
                                                     const float* __restrict__ dis,
                                                     const int* __restrict__ ptr,
                                                     const int* __restrict__ rows_s,
                                                     const float* __restrict__ ws_s,
                                                     const float* __restrict__ bias,
                                                     float* __restrict__ out, int n) {
    const int wid = threadIdx.x >> 6;
    const int lane = threadIdx.x & 63;
    const int half = lane >> 5;
    const int dlane = lane & 31;
    const int v = blockIdx.x * 4 + wid;
    if (v >= n) return;

    const int beg = __builtin_amdgcn_readfirstlane(ptr[v]);
    const int end = __builtin_amdgcn_readfirstlane(ptr[v + 1]);
    const float dv = dis[v];

    float acc0 = 0.f, acc1 = 0.f;
    int e = beg;
    int head = (beg + 3) & ~3;
    if (head > end) head = end;
    for (; e < head; ++e) {
        int r = rows_s[e];
        float w = half ? 0.f : ws_s[e];
        uint32 g = xwb[(size_t)r * 32 + dlane];
        acc0 += w * h2lo(g);
        acc1 += w * h2hi(g);
    }
#pragma unroll 2
    for (; e + 4 <= end; e += 4) {
        int4 r4 = *(const int4*)(rows_s + e);
        float4 w4 = *(const float4*)(ws_s + e);
        int rA = half ? r4.y : r4.x;
        float wA = half ? w4.y : w4.x;
        int rB = half ? r4.w : r4.z;
        float wB = half ? w4.w : w4.z;
        uint32 gA = xwb[(size_t)rA * 32 + dlane];
        uint32 gB = xwb[(size_t)rB * 32 + dlane];
        acc0 += wA * h2lo(gA); acc1 += wA * h2hi(gA);
        acc0 += wB * h2lo(gB); acc1 += wB * h2hi(gB);
    }
    if (e + 2 <= end) {
        int2 r2 = *(const int2*)(rows_s + e);
        float2 w2 = *(const float2*)(ws_s + e);
        int r = half ? r2.y : r2.x;
        float w = half ? w2.y : w2.x;
        uint32 g = xwb[(size_t)r * 32 + dlane];
        acc0 += w * h2lo(g);
        acc1 += w * h2hi(g);
        e += 2;
    }
    if (e < end) {
        int r = rows_s[e];
        float w = half ? 0.f : ws_s[e];
        uint32 g = xwb[(size_t)r * 32 + dlane];
        acc0 += w * h2lo(g);
        acc1 += w * h2hi(g);
    }
    acc0 += __shfl_xor(acc0, 32);
    acc1 += __shfl_xor(acc1, 32);

    if (lane < 32) {
        uint32 g = xwb[(size_t)v * 32 + lane];
        float r0 = dv * acc0 + dv * dv * h2lo(g) + bias[lane * 2];
        float r1 = dv * acc1 + dv * dv * h2hi(g) + bias[lane * 2 + 1];
        float2 o = {r0, r1};
        *(float2*)(out + (size_t)v * 64 + lane * 2) = o;
    }
}

extern "C" void kernel_launch(void* const* d_in, const int* in_sizes, int n_in,
                              void* d_out, int out_size, void* d_ws, size_t ws_size,
                              hipStream_t stream) {
    const float* x  = (const float*)d_in[0];
    const void*  ei = d_in[1];
    const float* ew = (const float*)d_in[2];
    const float* W1 = (const float*)d_in[3];
    const float* b1 = (const float*)d_in[4];
    const float* W2 = (const float*)d_in[5];
    const float* b2 = (const float*)d_in[6];
    float* out = (float*)d_out;

    const int n = in_sizes[0] / 128;
    const int E = in_sizes[2];
    const int NB = (n + NPB - 1) >> NPBSH;
    const int chunk = (E + PBLK - 1) / PBLK;

    char* p = (char*)d_ws;
    size_t o = 0;
    auto alloc = [&](size_t bytes) -> void* {
        void* q = p + o;
        o += (bytes + 255) & ~(size_t)255;
        return q;
    };
    int*    flag     = (int*)alloc(4);
    int*    cnt_bb   = (int*)alloc((size_t)PBLK * NB * 4);
    int*    boff_rel = (int*)alloc((size_t)PBLK * NB * 4);
    int*    tb       = (int*)alloc((size_t)NB * 4);
    int*    bstart   = (int*)alloc(((size_t)NB + 1) * 4);
    int*    ptr      = (int*)alloc(((size_t)n + 1) * 4);
    float*  dis      = (float*)alloc((size_t)n * 4);
    int2*   bktrec   = (int2*)alloc((size_t)E * 8);
    unsigned short* bktc = (unsigned short*)alloc((size_t)E * 2 + 16);
    int*    rows_s   = (int*)alloc(((size_t)E + 8) * 4);
    float*  ws_s     = (float*)alloc(((size_t)E + 8) * 4);
    uint32* bufA     = (uint32*)alloc((size_t)n * 64 * 4);  // xw1/xw2 fp16x2
    uint32* bufB     = (uint32*)alloc((size_t)n * 64 * 4);  // h fp16x2

    const int gblk = (n + 127) / 128;

    detect_kernel<<<1, 64, 0, stream>>>((const int*)ei, flag);
    p1_hist<<<PBLK, 512, NB * 4, stream>>>(ei, E, NB, chunk, flag, cnt_bb);
    s1_colscan<<<NB, PBLK, 0, stream>>>(cnt_bb, boff_rel, tb, NB);
    scan_kernel<<<1, 1024, 0, stream>>>(tb, bstart, NB);
    p2_scatter<<<PBLK, 512, NB * 4, stream>>>(ei, ew, E, NB, chunk, flag, bstart,
                                              boff_rel, bktrec, bktc);
    p3_build<<<NB, 256, 0, stream>>>(bstart, bktrec, bktc, ptr, rows_s, ws_s, dis, n, NB, E);
    fold_kernel<<<2048, 256, 0, stream>>>(rows_s, ws_s, dis, E);

    mgemm_kernel<128, false><<<gblk, 256, 0, stream>>>(x, W1, (unsigned short*)bufA, n);
    prop128_kernel<<<(n + 3) / 4, 256, 0, stream>>>(bufA, dis, ptr, rows_s, ws_s, b1, bufB, n);
    mgemm_kernel<64, true><<<gblk, 256, 0, stream>>>(bufB, W2, (unsigned short*)bufA, n);
    prop64_kernel<<<(n + 3) / 4, 256, 0, stream>>>(bufA, dis, ptr, rows_s, ws_s, b2, out, n);
}

// Round 9
// 233.410 us; speedup vs baseline: 3.6292x; 1.0992x over previous
//
#include <hip/hip_runtime.h>
#include <stdint.h>

typedef unsigned int uint32;
typedef _Float16 f16x8 __attribute__((ext_vector_type(8)));
typedef float f32x4 __attribute__((ext_vector_type(4)));

// ---------------------------------------------------------------------------
// GCN 2-layer: out = GCNConv(relu(GCNConv(x, W1,b1)), W2,b2)
// deg[c] = sum ew into c, dis = rsqrt(deg+1)
// agg[c] = dis[c] * sum_e( w_e * xw[row_e] ) + dis[c]^2 * xw[c],
//   w_e = dis[row_e]*ew_e pre-folded into ws_s.
// CSR via atomic-free 2-level bucket sort (64-node buckets). p1/p2 use an
// XCD-aware chunk mapping (chunk = (blk&7)*32 + blk>>3) so adjacent bucket
// regions are written by the same XCD's L2 (kills cross-XCD line bouncing).
// Records pack {row | class<<20, ew} in 8B (n < 2^20).
// GEMMs via mfma_f32_16x16x32_f16; xw/h tables packed fp16x2.
// ---------------------------------------------------------------------------

#define NPBSH 6
#define NPB 64
#define PBLK 256
#define CAP 2048

__global__ void detect_kernel(const int* __restrict__ ei, int* flag) {
    if (threadIdx.x == 0 && blockIdx.x == 0) {
        int z = 0;
        for (int i = 0; i < 16; ++i) z |= ei[2 * i + 1];
        *flag = (z == 0) ? 1 : 0;
    }
}

__device__ inline int chunk_map(int blk) {  // XCD-contiguous chunk assignment
    return (blk & 7) * (PBLK / 8) + (blk >> 3);
}

// p1: per-chunk bucket histogram (LDS), no global atomics.
__global__ __launch_bounds__(512) void p1_hist(const void* __restrict__ ei, int E, int NB,
                                               int chunk, const int* __restrict__ flag,
                                               int* __restrict__ cnt_bb) {
    extern __shared__ int h[];
    const int t = threadIdx.x;
    const int blk = chunk_map(blockIdx.x);
    for (int i = t; i < NB; i += 512) h[i] = 0;
    __syncthreads();
    const int is64 = *flag;
    const int* e32 = (const int*)ei;
    const long long* e64 = (const long long*)ei;
    const int e0 = blk * chunk;
    const int e1 = min(e0 + chunk, E);
    for (int e = e0 + t; e < e1; e += 512) {
        int c = is64 ? (int)e64[(size_t)E + e] : e32[(size_t)E + e];
        atomicAdd(&h[c >> NPBSH], 1);
    }
    __syncthreads();
    for (int i = t; i < NB; i += 512) cnt_bb[(size_t)blk * NB + i] = h[i];
}

// s1: per-bucket column scan over PBLK chunk-counts -> boff_rel + totals.
__global__ __launch_bounds__(PBLK) void s1_colscan(const int* __restrict__ cnt_bb,
                                                   int* __restrict__ boff_rel,
                                                   int* __restrict__ tb, int NB) {
    __shared__ int sm[PBLK];
    const int t = threadIdx.x, b = blockIdx.x;
    int v = cnt_bb[(size_t)t * NB + b];
    sm[t] = v;
    __syncthreads();
    for (int off = 1; off < PBLK; off <<= 1) {
        int u = (t >= off) ? sm[t - off] : 0;
        __syncthreads();
        sm[t] += u;
        __syncthreads();
    }
    boff_rel[(size_t)t * NB + b] = sm[t] - v;  // exclusive prefix over chunks
    if (t == PBLK - 1) tb[b] = sm[PBLK - 1];
}

// s2: single-block chunked exclusive scan (tb[0..n) -> ptr[0..n], ptr[n]=total).
__global__ __launch_bounds__(1024) void scan_kernel(const int* __restrict__ cnt,
                                                    int* __restrict__ ptr, int n) {
    __shared__ int sm[1024];
    const int t = threadIdx.x;
    const int chunk = (n + 1023) / 1024;
    const int start = t * chunk;
    const int end = min(start + chunk, n);
    int s = 0;
    for (int i = start; i < end; ++i) s += cnt[i];
    sm[t] = s;
    __syncthreads();
    for (int off = 1; off < 1024; off <<= 1) {
        int v = (t >= off) ? sm[t - off] : 0;
        __syncthreads();
        sm[t] += v;
        __syncthreads();
    }
    int run = (t == 0) ? 0 : sm[t - 1];
    for (int i = start; i < end; ++i) { ptr[i] = run; run += cnt[i]; }
    if (start < n && end == n) ptr[n] = run;
}

// p2: bucketed append; packed 8B records {row | cl<<20, ew_bits}.
__global__ __launch_bounds__(512) void p2_scatter(const void* __restrict__ ei,
                                                  const float* __restrict__ ew,
                                                  int E, int NB, int chunk,
                                                  const int* __restrict__ flag,
                                                  const int* __restrict__ bstart,
                                                  const int* __restrict__ boff_rel,
                                                  int2* __restrict__ bktrec) {
    extern __shared__ int cur[];
    const int t = threadIdx.x;
    const int blk = chunk_map(blockIdx.x);
    for (int i = t; i < NB; i += 512)
        cur[i] = bstart[i] + boff_rel[(size_t)blk * NB + i];
    __syncthreads();
    const int is64 = *flag;
    const int* e32 = (const int*)ei;
    const long long* e64 = (const long long*)ei;
    const int e0 = blk * chunk;
    const int e1 = min(e0 + chunk, E);
    for (int e = e0 + t; e < e1; e += 512) {
        int r, c;
        if (is64) { r = (int)e64[e]; c = (int)e64[(size_t)E + e]; }
        else      { r = e32[e];      c = e32[(size_t)E + e]; }
        int b = c >> NPBSH;
        int pos = atomicAdd(&cur[b], 1);
        bktrec[pos] = make_int2(r | ((c & (NPB - 1)) << 20), __float_as_int(ew[e]));
    }
}

// p3: per-bucket CSR build in LDS + ptr + fused deg/dis.
__global__ __launch_bounds__(256) void p3_build(const int* __restrict__ bstart,
                                                const int2* __restrict__ bktrec,
                                                int* __restrict__ ptr, int* __restrict__ rows_s,
                                                float* __restrict__ ws_s, float* __restrict__ dis,
                                                int n, int NB, int E) {
    __shared__ int inp[CAP];
    __shared__ float inw[CAP];
    __shared__ int outr[CAP];
    __shared__ float outw[CAP];
    __shared__ int h[NPB], ex[NPB + 1], cu[NPB];
    const int t = threadIdx.x, b = blockIdx.x;
    const int base = bstart[b];
    const int eb = bstart[b + 1] - base;
    const int j0 = b << NPBSH;
    const int ncount = min(NPB, n - j0);
    if (t < NPB) { h[t] = 0; cu[t] = 0; }
    __syncthreads();

    if (eb <= CAP) {
        for (int i = t; i < eb; i += 256) {
            int2 rc = bktrec[base + i];
            inp[i] = rc.x;
            inw[i] = __int_as_float(rc.y);
            atomicAdd(&h[(rc.x >> 20) & 63], 1);
        }
        __syncthreads();
        if (t == 0) {
            int run = 0;
            for (int j = 0; j < NPB; ++j) { ex[j] = run; run += h[j]; }
            ex[NPB] = run;
        }
        __syncthreads();
        for (int i = t; i < eb; i += 256) {
            int v = inp[i];
            int cl = (v >> 20) & 63;
            int d = ex[cl] + atomicAdd(&cu[cl], 1);
            outr[d] = v & 0xFFFFF;
            outw[d] = inw[i];
        }
        __syncthreads();
        for (int i = t; i < eb; i += 256) {
            rows_s[base + i] = outr[i];
            ws_s[base + i] = outw[i];
        }
        if (t < ncount) {
            ptr[j0 + t] = base + ex[t];
            float s = 0.f;
            for (int i = ex[t]; i < ex[t] + h[t]; ++i) s += outw[i];
            dis[j0 + t] = rsqrtf(s + 1.0f);
        }
    } else {  // fallback (eb > CAP): global two-pass, still correct
        for (int i = t; i < eb; i += 256) atomicAdd(&h[(bktrec[base + i].x >> 20) & 63], 1);
        __syncthreads();
        if (t == 0) {
            int run = 0;
            for (int j = 0; j < NPB; ++j) { ex[j] = run; run += h[j]; }
            ex[NPB] = run;
        }
        __syncthreads();
        for (int i = t; i < eb; i += 256) {
            int2 rc = bktrec[base + i];
            int cl = (rc.x >> 20) & 63;
            int d = ex[cl] + atomicAdd(&cu[cl], 1);
            rows_s[base + d] = rc.x & 0xFFFFF;
            ws_s[base + d] = __int_as_float(rc.y);
        }
        __syncthreads();
        if (t < ncount) {
            ptr[j0 + t] = base + ex[t];
            float s = 0.f;
            for (int i = base + ex[t]; i < base + ex[t] + h[t]; ++i) s += ws_s[i];
            dis[j0 + t] = rsqrtf(s + 1.0f);
        }
    }
    if (b == NB - 1 && t == 0) ptr[n] = E;
}

// Pre-fold dis[row] into the edge weight: ws_s[e] *= dis[rows_s[e]].
__global__ void fold_kernel(const int* __restrict__ rows_s, float* __restrict__ ws_s,
                            const float* __restrict__ dis, int E) {
    for (int e = blockIdx.x * blockDim.x + threadIdx.x; e < E;
         e += gridDim.x * blockDim.x)
        ws_s[e] *= dis[rows_s[e]];
}

__device__ inline uint32 pack2h(float a, float b) {
    unsigned short ua = __builtin_bit_cast(unsigned short, (_Float16)a);
    unsigned short ub = __builtin_bit_cast(unsigned short, (_Float16)b);
    return (uint32)ua | ((uint32)ub << 16);
}
__device__ inline float h2lo(uint32 g) {
    return (float)__builtin_bit_cast(_Float16, (unsigned short)(g & 0xFFFFu));
}
__device__ inline float h2hi(uint32 g) {
    return (float)__builtin_bit_cast(_Float16, (unsigned short)(g >> 16));
}

// Byte offset of fp16 element k within a 256B fragment-ordered row (same
// permutation applied to A and B keeps D = A*B invariant).
__device__ inline int kposb(int k) {
    return ((k >> 5) << 6) + (((k >> 2) & 3) << 4) + (((k >> 4) & 1) << 3) + ((k & 3) << 1);
}

// ---------------------------------------------------------------------------
// Y[n,DOUT] = X[n,128] @ W[128,DOUT] via mfma_f32_16x16x32_f16 (f32 accum).
// ---------------------------------------------------------------------------
template <int DOUT, bool PACKED>
__global__ __launch_bounds__(256, 2) void mgemm_kernel(const void* __restrict__ Xv,
                                                       const float* __restrict__ W,
                                                       unsigned short* __restrict__ Y,
                                                       int n) {
    constexpr int NC = DOUT / 16;
    __shared__ __align__(16) unsigned short Xl[128 * 128];
    __shared__ __align__(16) unsigned short Wl[DOUT * 128];
    const int t = threadIdx.x;
    const int row0 = blockIdx.x * 128;

    for (int i = t * 4; i < 128 * 128; i += 1024) {
        int r = i >> 7, k = i & 127;
        uint2 st;
        if (PACKED) {
            uint2 v = {0u, 0u};
            if (row0 + r < n)
                v = *(const uint2*)((const uint32*)Xv + (size_t)(row0 + r) * 64 + (k >> 1));
            st = v;
        } else {
            float4 v = {0.f, 0.f, 0.f, 0.f};
            if (row0 + r < n)
                v = *(const float4*)((const float*)Xv + (size_t)(row0 + r) * 128 + k);
            st.x = pack2h(v.x, v.y);
            st.y = pack2h(v.z, v.w);
        }
        *(uint2*)((char*)Xl + r * 256 + (kposb(k) ^ ((r & 7) << 4))) = st;
    }
    for (int i = t; i < 128 * (DOUT / 4); i += 256) {
        int k = i / (DOUT / 4);
        int c0 = (i % (DOUT / 4)) * 4;
        float4 wv = *(const float4*)(W + (size_t)k * DOUT + c0);
        float a[4] = {wv.x, wv.y, wv.z, wv.w};
        int kb = kposb(k);
#pragma unroll
        for (int j = 0; j < 4; ++j) {
            int c = c0 + j;
            *(unsigned short*)((char*)Wl + c * 256 + (kb ^ ((c & 7) << 4))) =
                __builtin_bit_cast(unsigned short, (_Float16)a[j]);
        }
    }
    __syncthreads();

    const int l = t & 63;
    const int w = t >> 6;
    const int lr = l & 15;
    const int lq = l >> 4;
    const int rbase = w * 32;
    const int swz = (lr & 7) << 4;

    f32x4 acc[2][NC];
#pragma unroll
    for (int i = 0; i < 2; ++i)
#pragma unroll
        for (int c = 0; c < NC; ++c) acc[i][c] = (f32x4){0.f, 0.f, 0.f, 0.f};

#pragma unroll
    for (int ks = 0; ks < 4; ++ks) {
        const int fo = ks * 64 + lq * 16;
        f16x8 a0 = *(const f16x8*)((const char*)Xl + (rbase + lr) * 256 + (fo ^ swz));
        f16x8 a1 = *(const f16x8*)((const char*)Xl + (rbase + 16 + lr) * 256 + (fo ^ swz));
#pragma unroll
        for (int c = 0; c < NC; ++c) {
            f16x8 b = *(const f16x8*)((const char*)Wl + (c * 16 + lr) * 256 + (fo ^ swz));
            acc[0][c] = __builtin_amdgcn_mfma_f32_16x16x32_f16(a0, b, acc[0][c], 0, 0, 0);
            acc[1][c] = __builtin_amdgcn_mfma_f32_16x16x32_f16(a1, b, acc[1][c], 0, 0, 0);
        }
    }

#pragma unroll
    for (int i = 0; i < 2; ++i) {
#pragma unroll
        for (int c = 0; c < NC; ++c) {
#pragma unroll
            for (int reg = 0; reg < 4; ++reg) {
                int row = row0 + rbase + i * 16 + lq * 4 + reg;
                if (row < n)
                    Y[(size_t)row * DOUT + c * 16 + lr] =
                        __builtin_bit_cast(unsigned short, (_Float16)acc[i][c][reg]);
            }
        }
    }
}

// One wave per node, D=128: lane covers dims 2*lane..2*lane+1 (one fp16x2).
__global__ __launch_bounds__(256) void prop128_kernel(const uint32* __restrict__ xwb,
                                                      const float* __restrict__ dis,
                                                      const int* __restrict__ ptr,
                                                      const int* __restrict__ rows_s,
                                                      const float* __restrict__ ws_s,
                                                      const float* __restrict__ bias,
                                                      uint32* __restrict__ out, int n) {
    const int wid = threadIdx.x >> 6;
    const int lane = threadIdx.x & 63;
    const int v = blockIdx.x * 4 + wid;
    if (v >= n) return;

    const int beg = __builtin_amdgcn_readfirstlane(ptr[v]);
    const int end = __builtin_amdgcn_readfirstlane(ptr[v + 1]);
    const float dv = dis[v];

    float acc0 = 0.f, acc1 = 0.f;
    int e = beg;
    int head = (beg + 3) & ~3;
    if (head > end) head = end;
    for (; e < head; ++e) {
        int r = rows_s[e];
        float w = ws_s[e];
        uint32 g = xwb[(size_t)r * 64 + lane];
        acc0 += w * h2lo(g);
        acc1 += w * h2hi(g);
    }
#pragma unroll 4
    for (; e + 4 <= end; e += 4) {
        int4 r4 = *(const int4*)(rows_s + e);
        float4 w4 = *(const float4*)(ws_s + e);
        uint32 g0 = xwb[(size_t)r4.x * 64 + lane];
        uint32 g1 = xwb[(size_t)r4.y * 64 + lane];
        uint32 g2 = xwb[(size_t)r4.z * 64 + lane];
        uint32 g3 = xwb[(size_t)r4.w * 64 + lane];
        acc0 += w4.x * h2lo(g0); acc1 += w4.x * h2hi(g0);
        acc0 += w4.y * h2lo(g1); acc1 += w4.y * h2hi(g1);
        acc0 += w4.z * h2lo(g2); acc1 += w4.z * h2hi(g2);
        acc0 += w4.w * h2lo(g3); acc1 += w4.w * h2hi(g3);
    }
    for (; e < end; ++e) {
        int r = rows_s[e];
        float w = ws_s[e];
        uint32 g = xwb[(size_t)r * 64 + lane];
        acc0 += w * h2lo(g);
        acc1 += w * h2hi(g);
    }

    uint32 g = xwb[(size_t)v * 64 + lane];
    float r0 = dv * acc0 + dv * dv * h2lo(g) + bias[lane * 2];
    float r1 = dv * acc1 + dv * dv * h2hi(g) + bias[lane * 2 + 1];
    r0 = fmaxf(r0, 0.f);
    r1 = fmaxf(r1, 0.f);
    out[(size_t)v * 64 + lane] = pack2h(r0, r1);
}

// One wave per node, D=64: lane halves process 2 edges/iter.
__global__ __launch_bounds__(256) void prop64_kernel(const uint32* __restrict__ xwb,
                                                     const float* __restrict__ dis,
                                                     const int* __restrict__ ptr,
                                                     const int* __restrict__ rows_s,
                                                     const float* __restrict__ ws_s,
                                                     const float* __restrict__ bias,
                                                     float* __restrict__ out, int n) {
    const int wid = threadIdx.x >> 6;
    const int lane = threadIdx.x & 63;
    const int half = lane >> 5;
    const int dlane = lane & 31;
    const int v = blockIdx.x * 4 + wid;
    if (v >= n) return;

    const int beg = __builtin_amdgcn_readfirstlane(ptr[v]);
    const int end = __builtin_amdgcn_readfirstlane(ptr[v + 1]);
    const float dv = dis[v];

    float acc0 = 0.f, acc1 = 0.f;
    int e = beg;
    int head = (beg + 3) & ~3;
    if (head > end) head = end;
    for (; e < head; ++e) {
        int r = rows_s[e];
        float w = half ? 0.f : ws_s[e];
        uint32 g = xwb[(size_t)r * 32 + dlane];
        acc0 += w * h2lo(g);
        acc1 += w * h2hi(g);
    }
#pragma unroll 4
    for (; e + 4 <= end; e += 4) {
        int4 r4 = *(const int4*)(rows_s + e);
        float4 w4 = *(const float4*)(ws_s + e);
        int rA = half ? r4.y : r4.x;
        float wA = half ? w4.y : w4.x;
        int rB = half ? r4.w : r4.z;
        float wB = half ? w4.w : w4.z;
        uint32 gA = xwb[(size_t)rA * 32 + dlane];
        uint32 gB = xwb[(size_t)rB * 32 + dlane];
        acc0 += wA * h2lo(gA); acc1 += wA * h2hi(gA);
        acc0 += wB * h2lo(gB); acc1 += wB * h2hi(gB);
    }
    if (e + 2 <= end) {
        int2 r2 = *(const int2*)(rows_s + e);
        float2 w2 = *(const float2*)(ws_s + e);
        int r = half ? r2.y : r2.x;
        float w = half ? w2.y : w2.x;
        uint32 g = xwb[(size_t)r * 32 + dlane];
        acc0 += w * h2lo(g);
        acc1 += w * h2hi(g);
        e += 2;
    }
    if (e < end) {
        int r = rows_s[e];
        float w = half ? 0.f : ws_s[e];
        uint32 g = xwb[(size_t)r * 32 + dlane];
        acc0 += w * h2lo(g);
        acc1 += w * h2hi(g);
    }
    acc0 += __shfl_xor(acc0, 32);
    acc1 += __shfl_xor(acc1, 32);

    if (lane < 32) {
        uint32 g = xwb[(size_t)v * 32 + lane];
        float r0 = dv * acc0 + dv * dv * h2lo(g) + bias[lane * 2];
        float r1 = dv * acc1 + dv * dv * h2hi(g) + bias[lane * 2 + 1];
        float2 o = {r0, r1};
        *(float2*)(out + (size_t)v * 64 + lane * 2) = o;
    }
}

extern "C" void kernel_launch(void* const* d_in, const int* in_sizes, int n_in,
                              void* d_out, int out_size, void* d_ws, size_t ws_size,
                              hipStream_t stream) {
    const float* x  = (const float*)d_in[0];
    const void*  ei = d_in[1];
    const float* ew = (const float*)d_in[2];
    const float* W1 = (const float*)d_in[3];
    const float* b1 = (const float*)d_in[4];
    const float* W2 = (const float*)d_in[5];
    const float* b2 = (const float*)d_in[6];
    float* out = (float*)d_out;

    const int n = in_sizes[0] / 128;
    const int E = in_sizes[2];
    const int NB = (n + NPB - 1) >> NPBSH;
    const int chunk = (E + PBLK - 1) / PBLK;

    char* p = (char*)d_ws;
    size_t o = 0;
    auto alloc = [&](size_t bytes) -> void* {
        void* q = p + o;
        o += (bytes + 255) & ~(size_t)255;
        return q;
    };
    int*    flag     = (int*)alloc(4);
    int*    cnt_bb   = (int*)alloc((size_t)PBLK * NB * 4);
    int*    boff_rel = (int*)alloc((size_t)PBLK * NB * 4);
    int*    tb       = (int*)alloc((size_t)NB * 4);
    int*    bstart   = (int*)alloc(((size_t)NB + 1) * 4);
    int*    ptr      = (int*)alloc(((size_t)n + 1) * 4);
    float*  dis      = (float*)alloc((size_t)n * 4);
    int2*   bktrec   = (int2*)alloc((size_t)E * 8);
    int*    rows_s   = (int*)alloc(((size_t)E + 8) * 4);
    float*  ws_s     = (float*)alloc(((size_t)E + 8) * 4);
    uint32* bufA     = (uint32*)alloc((size_t)n * 64 * 4);  // xw1/xw2 fp16x2
    uint32* bufB     = (uint32*)alloc((size_t)n * 64 * 4);  // h fp16x2

    const int gblk = (n + 127) / 128;

    detect_kernel<<<1, 64, 0, stream>>>((const int*)ei, flag);
    p1_hist<<<PBLK, 512, NB * 4, stream>>>(ei, E, NB, chunk, flag, cnt_bb);
    s1_colscan<<<NB, PBLK, 0, stream>>>(cnt_bb, boff_rel, tb, NB);
    scan_kernel<<<1, 1024, 0, stream>>>(tb, bstart, NB);
    p2_scatter<<<PBLK, 512, NB * 4, stream>>>(ei, ew, E, NB, chunk, flag, bstart,
                                              boff_rel, bktrec);
    p3_build<<<NB, 256, 0, stream>>>(bstart, bktrec, ptr, rows_s, ws_s, dis, n, NB, E);
    fold_kernel<<<2048, 256, 0, stream>>>(rows_s, ws_s, dis, E);

    mgemm_kernel<128, false><<<gblk, 256, 0, stream>>>(x, W1, (unsigned short*)bufA, n);
    prop128_kernel<<<(n + 3) / 4, 256, 0, stream>>>(bufA, dis, ptr, rows_s, ws_s, b1, bufB, n);
    mgemm_kernel<64, true><<<gblk, 256, 0, stream>>>(bufB, W2, (unsigned short*)bufA, n);
    prop64_kernel<<<(n + 3) / 4, 256, 0, stream>>>(bufA, dis, ptr, rows_s, ws_s, b2, out, n);
}

// Round 10
// 229.682 us; speedup vs baseline: 3.6881x; 1.0162x over previous
//
#include <hip/hip_runtime.h>
#include <stdint.h>

typedef unsigned int uint32;
typedef _Float16 f16x8 __attribute__((ext_vector_type(8)));
typedef float f32x4 __attribute__((ext_vector_type(4)));

// ---------------------------------------------------------------------------
// GCN 2-layer: out = GCNConv(relu(GCNConv(x, W1,b1)), W2,b2)
// deg[c] = sum ew into c, dis = rsqrt(deg+1)
// agg[c] = dis[c] * sum_e( w_e * xw[row_e] ) + dis[c]^2 * xw[c],
//   w_e = dis[row_e]*ew_e pre-folded into ws_s.
// CSR via atomic-free 2-level bucket sort (64-node buckets), XCD-aware chunk
// mapping in p1/p2. Records pack {row | class<<20, ew} (n < 2^20).
// GEMMs via mfma_f32_16x16x32_f16; xw/h tables packed fp16x2.
// Props gather multi-edge per instruction: prop128 = half-wave row (2 edges/
// gather), prop64 = quarter-wave row (4 edges/gather); shfl_xor combines.
// ---------------------------------------------------------------------------

#define NPBSH 6
#define NPB 64
#define PBLK 256
#define CAP 2048

__global__ void detect_kernel(const int* __restrict__ ei, int* flag) {
    if (threadIdx.x == 0 && blockIdx.x == 0) {
        int z = 0;
        for (int i = 0; i < 16; ++i) z |= ei[2 * i + 1];
        *flag = (z == 0) ? 1 : 0;
    }
}

__device__ inline int chunk_map(int blk) {  // XCD-contiguous chunk assignment
    return (blk & 7) * (PBLK / 8) + (blk >> 3);
}

// p1: per-chunk bucket histogram (LDS), no global atomics.
__global__ __launch_bounds__(512) void p1_hist(const void* __restrict__ ei, int E, int NB,
                                               int chunk, const int* __restrict__ flag,
                                               int* __restrict__ cnt_bb) {
    extern __shared__ int h[];
    const int t = threadIdx.x;
    const int blk = chunk_map(blockIdx.x);
    for (int i = t; i < NB; i += 512) h[i] = 0;
    __syncthreads();
    const int is64 = *flag;
    const int* e32 = (const int*)ei;
    const long long* e64 = (const long long*)ei;
    const int e0 = blk * chunk;
    const int e1 = min(e0 + chunk, E);
    for (int e = e0 + t; e < e1; e += 512) {
        int c = is64 ? (int)e64[(size_t)E + e] : e32[(size_t)E + e];
        atomicAdd(&h[c >> NPBSH], 1);
    }
    __syncthreads();
    for (int i = t; i < NB; i += 512) cnt_bb[(size_t)blk * NB + i] = h[i];
}

// s1: per-bucket column scan over PBLK chunk-counts -> boff_rel + totals.
__global__ __launch_bounds__(PBLK) void s1_colscan(const int* __restrict__ cnt_bb,
                                                   int* __restrict__ boff_rel,
                                                   int* __restrict__ tb, int NB) {
    __shared__ int sm[PBLK];
    const int t = threadIdx.x, b = blockIdx.x;
    int v = cnt_bb[(size_t)t * NB + b];
    sm[t] = v;
    __syncthreads();
    for (int off = 1; off < PBLK; off <<= 1) {
        int u = (t >= off) ? sm[t - off] : 0;
        __syncthreads();
        sm[t] += u;
        __syncthreads();
    }
    boff_rel[(size_t)t * NB + b] = sm[t] - v;  // exclusive prefix over chunks
    if (t == PBLK - 1) tb[b] = sm[PBLK - 1];
}

// s2: single-block chunked exclusive scan (tb[0..n) -> ptr[0..n], ptr[n]=total).
__global__ __launch_bounds__(1024) void scan_kernel(const int* __restrict__ cnt,
                                                    int* __restrict__ ptr, int n) {
    __shared__ int sm[1024];
    const int t = threadIdx.x;
    const int chunk = (n + 1023) / 1024;
    const int start = t * chunk;
    const int end = min(start + chunk, n);
    int s = 0;
    for (int i = start; i < end; ++i) s += cnt[i];
    sm[t] = s;
    __syncthreads();
    for (int off = 1; off < 1024; off <<= 1) {
        int v = (t >= off) ? sm[t - off] : 0;
        __syncthreads();
        sm[t] += v;
        __syncthreads();
    }
    int run = (t == 0) ? 0 : sm[t - 1];
    for (int i = start; i < end; ++i) { ptr[i] = run; run += cnt[i]; }
    if (start < n && end == n) ptr[n] = run;
}

// p2: bucketed append; packed 8B records {row | cl<<20, ew_bits}.
__global__ __launch_bounds__(512) void p2_scatter(const void* __restrict__ ei,
                                                  const float* __restrict__ ew,
                                                  int E, int NB, int chunk,
                                                  const int* __restrict__ flag,
                                                  const int* __restrict__ bstart,
                                                  const int* __restrict__ boff_rel,
                                                  int2* __restrict__ bktrec) {
    extern __shared__ int cur[];
    const int t = threadIdx.x;
    const int blk = chunk_map(blockIdx.x);
    for (int i = t; i < NB; i += 512)
        cur[i] = bstart[i] + boff_rel[(size_t)blk * NB + i];
    __syncthreads();
    const int is64 = *flag;
    const int* e32 = (const int*)ei;
    const long long* e64 = (const long long*)ei;
    const int e0 = blk * chunk;
    const int e1 = min(e0 + chunk, E);
    for (int e = e0 + t; e < e1; e += 512) {
        int r, c;
        if (is64) { r = (int)e64[e]; c = (int)e64[(size_t)E + e]; }
        else      { r = e32[e];      c = e32[(size_t)E + e]; }
        int b = c >> NPBSH;
        int pos = atomicAdd(&cur[b], 1);
        bktrec[pos] = make_int2(r | ((c & (NPB - 1)) << 20), __float_as_int(ew[e]));
    }
}

// p3: per-bucket CSR build in LDS + ptr + fused deg/dis.
__global__ __launch_bounds__(256) void p3_build(const int* __restrict__ bstart,
                                                const int2* __restrict__ bktrec,
                                                int* __restrict__ ptr, int* __restrict__ rows_s,
                                                float* __restrict__ ws_s, float* __restrict__ dis,
                                                int n, int NB, int E) {
    __shared__ int inp[CAP];
    __shared__ float inw[CAP];
    __shared__ int outr[CAP];
    __shared__ float outw[CAP];
    __shared__ int h[NPB], ex[NPB + 1], cu[NPB];
    const int t = threadIdx.x, b = blockIdx.x;
    const int base = bstart[b];
    const int eb = bstart[b + 1] - base;
    const int j0 = b << NPBSH;
    const int ncount = min(NPB, n - j0);
    if (t < NPB) { h[t] = 0; cu[t] = 0; }
    __syncthreads();

    if (eb <= CAP) {
        for (int i = t; i < eb; i += 256) {
            int2 rc = bktrec[base + i];
            inp[i] = rc.x;
            inw[i] = __int_as_float(rc.y);
            atomicAdd(&h[(rc.x >> 20) & 63], 1);
        }
        __syncthreads();
        if (t == 0) {
            int run = 0;
            for (int j = 0; j < NPB; ++j) { ex[j] = run; run += h[j]; }
            ex[NPB] = run;
        }
        __syncthreads();
        for (int i = t; i < eb; i += 256) {
            int v = inp[i];
            int cl = (v >> 20) & 63;
            int d = ex[cl] + atomicAdd(&cu[cl], 1);
            outr[d] = v & 0xFFFFF;
            outw[d] = inw[i];
        }
        __syncthreads();
        for (int i = t; i < eb; i += 256) {
            rows_s[base + i] = outr[i];
            ws_s[base + i] = outw[i];
        }
        if (t < ncount) {
            ptr[j0 + t] = base + ex[t];
            float s = 0.f;
            for (int i = ex[t]; i < ex[t] + h[t]; ++i) s += outw[i];
            dis[j0 + t] = rsqrtf(s + 1.0f);
        }
    } else {  // fallback (eb > CAP): global two-pass, still correct
        for (int i = t; i < eb; i += 256) atomicAdd(&h[(bktrec[base + i].x >> 20) & 63], 1);
        __syncthreads();
        if (t == 0) {
            int run = 0;
            for (int j = 0; j < NPB; ++j) { ex[j] = run; run += h[j]; }
            ex[NPB] = run;
        }
        __syncthreads();
        for (int i = t; i < eb; i += 256) {
            int2 rc = bktrec[base + i];
            int cl = (rc.x >> 20) & 63;
            int d = ex[cl] + atomicAdd(&cu[cl], 1);
            rows_s[base + d] = rc.x & 0xFFFFF;
            ws_s[base + d] = __int_as_float(rc.y);
        }
        __syncthreads();
        if (t < ncount) {
            ptr[j0 + t] = base + ex[t];
            float s = 0.f;
            for (int i = base + ex[t]; i < base + ex[t] + h[t]; ++i) s += ws_s[i];
            dis[j0 + t] = rsqrtf(s + 1.0f);
        }
    }
    if (b == NB - 1 && t == 0) ptr[n] = E;
    if (b == NB - 1 && t < 8) {  // zero pad so masked over-reads see index 0
        rows_s[E + t] = 0;
        ws_s[E + t] = 0.f;
    }
}

// Pre-fold dis[row] into the edge weight: ws_s[e] *= dis[rows_s[e]].
__global__ void fold_kernel(const int* __restrict__ rows_s, float* __restrict__ ws_s,
                            const float* __restrict__ dis, int E) {
    for (int e = blockIdx.x * blockDim.x + threadIdx.x; e < E;
         e += gridDim.x * blockDim.x)
        ws_s[e] *= dis[rows_s[e]];
}

__device__ inline uint32 pack2h(float a, float b) {
    unsigned short ua = __builtin_bit_cast(unsigned short, (_Float16)a);
    unsigned short ub = __builtin_bit_cast(unsigned short, (_Float16)b);
    return (uint32)ua | ((uint32)ub << 16);
}
__device__ inline float h2lo(uint32 g) {
    return (float)__builtin_bit_cast(_Float16, (unsigned short)(g & 0xFFFFu));
}
__device__ inline float h2hi(uint32 g) {
    return (float)__builtin_bit_cast(_Float16, (unsigned short)(g >> 16));
}

// Byte offset of fp16 element k within a 256B fragment-ordered row (same
// permutation applied to A and B keeps D = A*B invariant).
__device__ inline int kposb(int k) {
    return ((k >> 5) << 6) + (((k >> 2) & 3) << 4) + (((k >> 4) & 1) << 3) + ((k & 3) << 1);
}

// ---------------------------------------------------------------------------
// Y[n,DOUT] = X[n,128] @ W[128,DOUT] via mfma_f32_16x16x32_f16 (f32 accum).
// ---------------------------------------------------------------------------
template <int DOUT, bool PACKED>
__global__ __launch_bounds__(256, 2) void mgemm_kernel(const void* __restrict__ Xv,
                                                       const float* __restrict__ W,
                                                       unsigned short* __restrict__ Y,
                                                       int n) {
    constexpr int NC = DOUT / 16;
    __shared__ __align__(16) unsigned short Xl[128 * 128];
    __shared__ __align__(16) unsigned short Wl[DOUT * 128];
    const int t = threadIdx.x;
    const int row0 = blockIdx.x * 128;

    for (int i = t * 4; i < 128 * 128; i += 1024) {
        int r = i >> 7, k = i & 127;
        uint2 st;
        if (PACKED) {
            uint2 v = {0u, 0u};
            if (row0 + r < n)
                v = *(const uint2*)((const uint32*)Xv + (size_t)(row0 + r) * 64 + (k >> 1));
            st = v;
        } else {
            float4 v = {0.f, 0.f, 0.f, 0.f};
            if (row0 + r < n)
                v = *(const float4*)((const float*)Xv + (size_t)(row0 + r) * 128 + k);
            st.x = pack2h(v.x, v.y);
            st.y = pack2h(v.z, v.w);
        }
        *(uint2*)((char*)Xl + r * 256 + (kposb(k) ^ ((r & 7) << 4))) = st;
    }
    for (int i = t; i < 128 * (DOUT / 4); i += 256) {
        int k = i / (DOUT / 4);
        int c0 = (i % (DOUT / 4)) * 4;
        float4 wv = *(const float4*)(W + (size_t)k * DOUT + c0);
        float a[4] = {wv.x, wv.y, wv.z, wv.w};
        int kb = kposb(k);
#pragma unroll
        for (int j = 0; j < 4; ++j) {
            int c = c0 + j;
            *(unsigned short*)((char*)Wl + c * 256 + (kb ^ ((c & 7) << 4))) =
                __builtin_bit_cast(unsigned short, (_Float16)a[j]);
        }
    }
    __syncthreads();

    const int l = t & 63;
    const int w = t >> 6;
    const int lr = l & 15;
    const int lq = l >> 4;
    const int rbase = w * 32;
    const int swz = (lr & 7) << 4;

    f32x4 acc[2][NC];
#pragma unroll
    for (int i = 0; i < 2; ++i)
#pragma unroll
        for (int c = 0; c < NC; ++c) acc[i][c] = (f32x4){0.f, 0.f, 0.f, 0.f};

#pragma unroll
    for (int ks = 0; ks < 4; ++ks) {
        const int fo = ks * 64 + lq * 16;
        f16x8 a0 = *(const f16x8*)((const char*)Xl + (rbase + lr) * 256 + (fo ^ swz));
        f16x8 a1 = *(const f16x8*)((const char*)Xl + (rbase + 16 + lr) * 256 + (fo ^ swz));
#pragma unroll
        for (int c = 0; c < NC; ++c) {
            f16x8 b = *(const f16x8*)((const char*)Wl + (c * 16 + lr) * 256 + (fo ^ swz));
            acc[0][c] = __builtin_amdgcn_mfma_f32_16x16x32_f16(a0, b, acc[0][c], 0, 0, 0);
            acc[1][c] = __builtin_amdgcn_mfma_f32_16x16x32_f16(a1, b, acc[1][c], 0, 0, 0);
        }
    }

#pragma unroll
    for (int i = 0; i < 2; ++i) {
#pragma unroll
        for (int c = 0; c < NC; ++c) {
#pragma unroll
            for (int reg = 0; reg < 4; ++reg) {
                int row = row0 + rbase + i * 16 + lq * 4 + reg;
                if (row < n)
                    Y[(size_t)row * DOUT + c * 16 + lr] =
                        __builtin_bit_cast(unsigned short, (_Float16)acc[i][c][reg]);
            }
        }
    }
}

// One wave per node, D=128. Half-wave per row: lane reads uint2 (4 dims),
// 2 edges per gather instruction; shfl_xor(32) combine. Aligned 2-edge
// groups with w=0 masking (rows_s zero-padded past E).
__global__ __launch_bounds__(256) void prop128_kernel(const uint32* __restrict__ xwb,
                                                      const float* __restrict__ dis,
                                                      const int* __restrict__ ptr,
                                                      const int* __restrict__ rows_s,
                                                      const float* __restrict__ ws_s,
                                                      const float* __restrict__ bias,
                                                      uint32* __restrict__ out, int n) {
    const int wid = threadIdx.x >> 6;
    const int lane = threadIdx.x & 63;
    const int half = lane >> 5;
    const int dlane = lane & 31;
    const int v = blockIdx.x * 4 + wid;
    if (v >= n) return;

    const int beg = __builtin_amdgcn_readfirstlane(ptr[v]);
    const int end = __builtin_amdgcn_readfirstlane(ptr[v + 1]);
    const float dv = dis[v];

    float a0 = 0.f, a1 = 0.f, a2 = 0.f, a3 = 0.f;
#pragma unroll 4
    for (int g = beg & ~1; g < end; g += 2) {
        int2 r2 = *(const int2*)(rows_s + g);
        float2 w2 = *(const float2*)(ws_s + g);
        int e = g + half;
        int r = half ? r2.y : r2.x;
        float w = half ? w2.y : w2.x;
        w = (e >= beg && e < end) ? w : 0.f;
        uint2 q = *(const uint2*)(xwb + (size_t)r * 64 + dlane * 2);
        a0 += w * h2lo(q.x);
        a1 += w * h2hi(q.x);
        a2 += w * h2lo(q.y);
        a3 += w * h2hi(q.y);
    }
    a0 += __shfl_xor(a0, 32);
    a1 += __shfl_xor(a1, 32);
    a2 += __shfl_xor(a2, 32);
    a3 += __shfl_xor(a3, 32);

    if (half == 0) {
        uint2 q = *(const uint2*)(xwb + (size_t)v * 64 + dlane * 2);
        float4 bi = *(const float4*)(bias + dlane * 4);
        float r0 = dv * a0 + dv * dv * h2lo(q.x) + bi.x;
        float r1 = dv * a1 + dv * dv * h2hi(q.x) + bi.y;
        float r2 = dv * a2 + dv * dv * h2lo(q.y) + bi.z;
        float r3 = dv * a3 + dv * dv * h2hi(q.y) + bi.w;
        r0 = fmaxf(r0, 0.f);
        r1 = fmaxf(r1, 0.f);
        r2 = fmaxf(r2, 0.f);
        r3 = fmaxf(r3, 0.f);
        uint2 o = {pack2h(r0, r1), pack2h(r2, r3)};
        *(uint2*)(out + (size_t)v * 64 + dlane * 2) = o;
    }
}

// One wave per node, D=64. Quarter-wave per row: lane reads uint2 (4 dims),
// 4 edges per gather instruction; shfl_xor(16/32) combine. f32 output.
__global__ __launch_bounds__(256) void prop64_kernel(const uint32* __restrict__ xwb,
                                                     const float* __restrict__ dis,
                                                     const int* __restrict__ ptr,
                                                     const int* __restrict__ rows_s,
                                                     const float* __restrict__ ws_s,
                                                     const float* __restrict__ bias,
                                                     float* __restrict__ out, int n) {
    const int wid = threadIdx.x >> 6;
    const int lane = threadIdx.x & 63;
    const int q4 = lane >> 4;
    const int dlane = lane & 15;
    const int v = blockIdx.x * 4 + wid;
    if (v >= n) return;

    const int beg = __builtin_amdgcn_readfirstlane(ptr[v]);
    const int end = __builtin_amdgcn_readfirstlane(ptr[v + 1]);
    const float dv = dis[v];

    float a0 = 0.f, a1 = 0.f, a2 = 0.f, a3 = 0.f;
#pragma unroll 4
    for (int g = beg & ~3; g < end; g += 4) {
        int4 r4 = *(const int4*)(rows_s + g);
        float4 w4 = *(const float4*)(ws_s + g);
        int e = g + q4;
        int r = (q4 & 2) ? ((q4 & 1) ? r4.w : r4.z) : ((q4 & 1) ? r4.y : r4.x);
        float w = (q4 & 2) ? ((q4 & 1) ? w4.w : w4.z) : ((q4 & 1) ? w4.y : w4.x);
        w = (e >= beg && e < end) ? w : 0.f;
        uint2 q = *(const uint2*)(xwb + (size_t)r * 32 + dlane * 2);
        a0 += w * h2lo(q.x);
        a1 += w * h2hi(q.x);
        a2 += w * h2lo(q.y);
        a3 += w * h2hi(q.y);
    }
    a0 += __shfl_xor(a0, 16);
    a1 += __shfl_xor(a1, 16);
    a2 += __shfl_xor(a2, 16);
    a3 += __shfl_xor(a3, 16);
    a0 += __shfl_xor(a0, 32);
    a1 += __shfl_xor(a1, 32);
    a2 += __shfl_xor(a2, 32);
    a3 += __shfl_xor(a3, 32);

    if (lane < 16) {
        uint2 q = *(const uint2*)(xwb + (size_t)v * 32 + dlane * 2);
        float4 bi = *(const float4*)(bias + dlane * 4);
        float4 o;
        o.x = dv * a0 + dv * dv * h2lo(q.x) + bi.x;
        o.y = dv * a1 + dv * dv * h2hi(q.x) + bi.y;
        o.z = dv * a2 + dv * dv * h2lo(q.y) + bi.z;
        o.w = dv * a3 + dv * dv * h2hi(q.y) + bi.w;
        *(float4*)(out + (size_t)v * 64 + dlane * 4) = o;
    }
}

extern "C" void kernel_launch(void* const* d_in, const int* in_sizes, int n_in,
                              void* d_out, int out_size, void* d_ws, size_t ws_size,
                              hipStream_t stream) {
    const float* x  = (const float*)d_in[0];
    const void*  ei = d_in[1];
    const float* ew = (const float*)d_in[2];
    const float* W1 = (const float*)d_in[3];
    const float* b1 = (const float*)d_in[4];
    const float* W2 = (const float*)d_in[5];
    const float* b2 = (const float*)d_in[6];
    float* out = (float*)d_out;

    const int n = in_sizes[0] / 128;
    const int E = in_sizes[2];
    const int NB = (n + NPB - 1) >> NPBSH;
    const int chunk = (E + PBLK - 1) / PBLK;

    char* p = (char*)d_ws;
    size_t o = 0;
    auto alloc = [&](size_t bytes) -> void* {
        void* q = p + o;
        o += (bytes + 255) & ~(size_t)255;
        return q;
    };
    int*    flag     = (int*)alloc(4);
    int*    cnt_bb   = (int*)alloc((size_t)PBLK * NB * 4);
    int*    boff_rel = (int*)alloc((size_t)PBLK * NB * 4);
    int*    tb       = (int*)alloc((size_t)NB * 4);
    int*    bstart   = (int*)alloc(((size_t)NB + 1) * 4);
    int*    ptr      = (int*)alloc(((size_t)n + 1) * 4);
    float*  dis      = (float*)alloc((size_t)n * 4);
    int2*   bktrec   = (int2*)alloc((size_t)E * 8);
    int*    rows_s   = (int*)alloc(((size_t)E + 8) * 4);
    float*  ws_s     = (float*)alloc(((size_t)E + 8) * 4);
    uint32* bufA     = (uint32*)alloc((size_t)n * 64 * 4);  // xw1/xw2 fp16x2
    uint32* bufB     = (uint32*)alloc((size_t)n * 64 * 4);  // h fp16x2

    const int gblk = (n + 127) / 128;

    detect_kernel<<<1, 64, 0, stream>>>((const int*)ei, flag);
    p1_hist<<<PBLK, 512, NB * 4, stream>>>(ei, E, NB, chunk, flag, cnt_bb);
    s1_colscan<<<NB, PBLK, 0, stream>>>(cnt_bb, boff_rel, tb, NB);
    scan_kernel<<<1, 1024, 0, stream>>>(tb, bstart, NB);
    p2_scatter<<<PBLK, 512, NB * 4, stream>>>(ei, ew, E, NB, chunk, flag, bstart,
                                              boff_rel, bktrec);
    p3_build<<<NB, 256, 0, stream>>>(bstart, bktrec, ptr, rows_s, ws_s, dis, n, NB, E);
    fold_kernel<<<2048, 256, 0, stream>>>(rows_s, ws_s, dis, E);

    mgemm_kernel<128, false><<<gblk, 256, 0, stream>>>(x, W1, (unsigned short*)bufA, n);
    prop128_kernel<<<(n + 3) / 4, 256, 0, stream>>>(bufA, dis, ptr, rows_s, ws_s, b1, bufB, n);
    mgemm_kernel<64, true><<<gblk, 256, 0, stream>>>(bufB, W2, (unsigned short*)bufA, n);
    prop64_kernel<<<(n + 3) / 4, 256, 0, stream>>>(bufA, dis, ptr, rows_s, ws_s, b2, out, n);
}